// Round 10
// baseline (63.379 us; speedup 1.0000x reference)
//
#include <hip/hip_runtime.h>
#include <hip/hip_bf16.h>
#include <cstdint>

typedef short bf16x8 __attribute__((ext_vector_type(8)));
typedef float f32x4 __attribute__((ext_vector_type(4)));

// Problem constants: B=2, DIM=128, H=64, W=64, DH=32, HEADS=4, K=7
#define NTOK 8192
#define QSCALE 0.17677669529663687f

__device__ inline float b2f(short s) {
  return __uint_as_float(((unsigned)(unsigned short)s) << 16);
}
__device__ inline short f2bs(float x) {
  __hip_bfloat16 b = __float2bfloat16(x);
  return *reinterpret_cast<short*>(&b);
}
__device__ inline bf16x8 ld8(const short* p) {
  short4 lo = *reinterpret_cast<const short4*>(p);
  short4 hi = *reinterpret_cast<const short4*>(p + 4);
  bf16x8 r;
  r[0] = lo.x; r[1] = lo.y; r[2] = lo.z; r[3] = lo.w;
  r[4] = hi.x; r[5] = hi.y; r[6] = hi.z; r[7] = hi.w;
  return r;
}
__device__ inline bf16x8 cvt8(float4 a, float4 c) {
  bf16x8 r;
  r[0] = f2bs(a.x); r[1] = f2bs(a.y); r[2] = f2bs(a.z); r[3] = f2bs(a.w);
  r[4] = f2bs(c.x); r[5] = f2bs(c.y); r[6] = f2bs(c.z); r[7] = f2bs(c.w);
  return r;
}

// ---------------- K1: tail-weight convert + NCHW->NHWC + LN1 + QKV GEMM ----------------
__global__ __launch_bounds__(256) void k_qkvcw(
    const float* __restrict__ x, const float* __restrict__ g,
    const float* __restrict__ be, const float* __restrict__ qkv_b,
    const float* __restrict__ qkv_w, const float* __restrict__ pw,
    const float* __restrict__ w1f, const float* __restrict__ w2f,
    const float* __restrict__ w3f, __hip_bfloat16* __restrict__ wb,
    float* __restrict__ r, __hip_bfloat16* __restrict__ qkvb) {
  __shared__ float xt[128][33];
  __shared__ __hip_bfloat16 at[32][136];
  int t = threadIdx.x;
  // --- prologue: convert tail weights (65536 elems over 256 blocks) ---
  {
    int ci = blockIdx.x * 256 + t;
    float cv;
    if (ci < 16384) cv = pw[ci];
    else if (ci < 32768) cv = w1f[ci - 16384];
    else if (ci < 49152) cv = w2f[ci - 32768];
    else cv = w3f[ci - 49152];
    wb[ci] = __float2bfloat16(cv);
  }
  int m0 = blockIdx.x * 32;
  int b = m0 >> 12;
  int p0 = m0 & 4095;
  const float* xb = x + (size_t)b * 524288;
  int tw = t & 31, th = t >> 5;
#pragma unroll
  for (int i = 0; i < 16; ++i) {
    int c = i * 8 + th;
    xt[c][tw] = xb[c * 4096 + p0 + tw];
  }
  __syncthreads();
  int wid = t >> 6, lane = t & 63;
  float gg0 = g[lane], gg1 = g[lane + 64];
  float bb0 = be[lane], bb1 = be[lane + 64];
#pragma unroll
  for (int it = 0; it < 8; ++it) {
    int tt = wid * 8 + it;
    float v0 = xt[lane][tt], v1 = xt[lane + 64][tt];
    float s = v0 + v1, sq = v0 * v0 + v1 * v1;
#pragma unroll
    for (int off = 32; off; off >>= 1) {
      s += __shfl_xor(s, off);
      sq += __shfl_xor(sq, off);
    }
    float mu = s * (1.f / 128.f);
    float var = sq * (1.f / 128.f) - mu * mu;
    float rs = rsqrtf(var + 1e-5f);
    r[(size_t)(m0 + tt) * 128 + lane] = v0;
    r[(size_t)(m0 + tt) * 128 + 64 + lane] = v1;
    at[tt][lane] = __float2bfloat16((v0 - mu) * rs * gg0 + bb0);
    at[tt][lane + 64] = __float2bfloat16((v1 - mu) * rs * gg1 + bb1);
  }
  __syncthreads();
  int mw = wid >> 1, nw = wid & 1;
  int lr = lane & 15, kg = lane >> 4;
  bf16x8 af[4];
#pragma unroll
  for (int ks = 0; ks < 4; ++ks)
    af[ks] = *reinterpret_cast<const bf16x8*>(&at[mw * 16 + lr][ks * 32 + kg * 8]);
  f32x4 acc[12];
#pragma unroll
  for (int nf = 0; nf < 12; ++nf) acc[nf] = f32x4{0, 0, 0, 0};
#pragma unroll
  for (int nf = 0; nf < 12; ++nf) {
    int o = nw * 192 + nf * 16 + lr;
    const float* wp = qkv_w + o * 128 + kg * 8;
#pragma unroll
    for (int ks = 0; ks < 4; ++ks) {
      float4 wa = *reinterpret_cast<const float4*>(wp + ks * 32);
      float4 wc = *reinterpret_cast<const float4*>(wp + ks * 32 + 4);
      acc[nf] = __builtin_amdgcn_mfma_f32_16x16x32_bf16(af[ks], cvt8(wa, wc),
                                                        acc[nf], 0, 0, 0);
    }
  }
#pragma unroll
  for (int nf = 0; nf < 12; ++nf) {
    int o = nw * 192 + nf * 16 + lr;
    float bv = qkv_b[o];
    float qs = (o < 128) ? QSCALE : 1.f;
#pragma unroll
    for (int rr = 0; rr < 4; ++rr) {
      int m = m0 + mw * 16 + kg * 4 + rr;
      qkvb[(size_t)m * 384 + o] = __float2bfloat16((acc[nf][rr] + bv) * qs);
    }
  }
}

// ---------------- K2: fused attn (R7-proven dataflow, 4 strips) + tail ----------------
// BISECT: attention staging/compute is verbatim R7 k_attn3 (staged Kl + Vt,
// per-strip pads, R7 barriers); only the strip loop + abuf output differ.
#define NB 98
#define KP 132
#define VP 108
#define PP 132
__global__ __launch_bounds__(256) void k_fuse2(
    const __hip_bfloat16* __restrict__ qkvb, const float* __restrict__ rpb,
    const float* __restrict__ r, const __hip_bfloat16* __restrict__ wb,
    const float* __restrict__ bproj,
    const float* __restrict__ g2, const float* __restrict__ be2,
    const float* __restrict__ b1,
    const float* __restrict__ g3, const float* __restrict__ be3,
    const float* __restrict__ b2,
    const float* __restrict__ g4, const float* __restrict__ be4,
    const float* __restrict__ b3, float* __restrict__ out) {
  __shared__ __align__(16) short smem[104 * KP + 128 * VP + 4 * 8 * PP];
  __shared__ __align__(16) __hip_bfloat16 abuf[32][136];
  __shared__ float2 red[2][2][16];
  short* Kl = smem;                   // [104][KP], rows 0..97 staged
  short* Vt = smem + 104 * KP;        // [128][VP] transposed V
  short* Pl = Vt + 128 * VP;          // [4][8][PP]
  const short* qs = (const short*)qkvb;
  int tid = threadIdx.x;
  int m0 = blockIdx.x * 32;
  int b = m0 >> 12, hq = (m0 >> 6) & 63;
  int hs = min(max(hq - 3, 0), 57);
  int h = tid >> 6, lane = tid & 63;
  int lr = lane & 15, kg = lane >> 4;
  const __hip_bfloat16* wproj = wb;
  const __hip_bfloat16* w1 = wb + 16384;
  const __hip_bfloat16* w2 = wb + 32768;
  const __hip_bfloat16* w3 = wb + 49152;

  // one-time Vt pad: cols 98..107 zero (never overwritten by staging)
  {
    int rowz = tid >> 1, halfz = tid & 1;
#pragma unroll
    for (int e = 0; e < 5; ++e) Vt[rowz * VP + NB + halfz * 5 + e] = 0;
  }

  for (int s = 0; s < 4; ++s) {
    __syncthreads();  // prev strip's QK^T/PV reads done -> Kl/Vt writable; pad visible
    int ms = m0 + s * 8;
    int c0s = (m0 & 63) + s * 8;
    int cs0 = min(max(c0s - 3, 0), 50);
    // ---- stage K rows + V transposed (R7 verbatim) ----
#pragma unroll
    for (int it = 0; it < 7; ++it) {
      int idx = it * 256 + tid;
      if (idx < NB * 16) {
        int row = idx >> 4, sub = idx & 15;
        int rh = row / 14, rc = row - rh * 14;
        int tr = b * 4096 + (hs + rh) * 64 + min(cs0 + rc, 63);
        const short* src = qs + (size_t)tr * 384 + 128 + sub * 8;
        *(short4*)(Kl + row * KP + sub * 8) = *(const short4*)src;
        *(short4*)(Kl + row * KP + sub * 8 + 4) = *(const short4*)(src + 4);
        const short* sv = qs + (size_t)tr * 384 + 256 + sub * 8;
        short4 vlo = *(const short4*)sv;
        short4 vhi = *(const short4*)(sv + 4);
        int d0 = sub * 8;
        Vt[(d0 + 0) * VP + row] = vlo.x;
        Vt[(d0 + 1) * VP + row] = vlo.y;
        Vt[(d0 + 2) * VP + row] = vlo.z;
        Vt[(d0 + 3) * VP + row] = vlo.w;
        Vt[(d0 + 4) * VP + row] = vhi.x;
        Vt[(d0 + 5) * VP + row] = vhi.y;
        Vt[(d0 + 6) * VP + row] = vhi.z;
        Vt[(d0 + 7) * VP + row] = vhi.w;
      }
    }
    __syncthreads();  // staged
    // ---- QK^T: 7 MFMAs, B from staged Kl (R7 verbatim) ----
    int qrow = min(ms + lr, NTOK - 1);
    bf16x8 aq = *reinterpret_cast<const bf16x8*>(qs + (size_t)qrow * 384 + h * 32 + kg * 8);
    f32x4 sc[7];
#pragma unroll
    for (int nt = 0; nt < 7; ++nt) {
      bf16x8 bk = ld8(Kl + (nt * 16 + lr) * KP + h * 32 + kg * 8);
      sc[nt] = __builtin_amdgcn_mfma_f32_16x16x32_bf16(aq, bk, f32x4{0, 0, 0, 0}, 0, 0, 0);
    }
    // ---- rpb + mask + softmax (R7 verbatim) ----
    int offv[4], cmt[4];
#pragma unroll
    for (int rr = 0; rr < 4; ++rr) {
      int ct = c0s + kg * 4 + rr;
      int ws0 = min(max(ct - 3, 0), 57);
      offv[rr] = ws0 - cs0;
      cmt[rr] = cs0 + 6 - ct;
    }
    float mx[4] = {-3e38f, -3e38f, -3e38f, -3e38f};
#pragma unroll
    for (int nt = 0; nt < 7; ++nt) {
      int nbr = nt * 16 + lr;
      int rh = nbr / 14, rc = nbr - rh * 14;
      bool vn = nbr < NB;
      int ribase = h * 169 + (hs - hq + 6 + rh) * 13 + rc;
#pragma unroll
      for (int rr = 0; rr < 4; ++rr) {
        float v = -1e30f;
        if (vn && (unsigned)(rc - offv[rr]) < 7u) v = sc[nt][rr] + rpb[ribase + cmt[rr]];
        sc[nt][rr] = v;
        mx[rr] = fmaxf(mx[rr], v);
      }
    }
#pragma unroll
    for (int rr = 0; rr < 4; ++rr) {
      mx[rr] = fmaxf(mx[rr], __shfl_xor(mx[rr], 1));
      mx[rr] = fmaxf(mx[rr], __shfl_xor(mx[rr], 2));
      mx[rr] = fmaxf(mx[rr], __shfl_xor(mx[rr], 4));
      mx[rr] = fmaxf(mx[rr], __shfl_xor(mx[rr], 8));
    }
    float sum[4] = {0.f, 0.f, 0.f, 0.f};
#pragma unroll
    for (int nt = 0; nt < 7; ++nt)
#pragma unroll
      for (int rr = 0; rr < 4; ++rr) {
        float e = __expf(sc[nt][rr] - mx[rr]);
        sc[nt][rr] = e;
        sum[rr] += e;
      }
#pragma unroll
    for (int rr = 0; rr < 4; ++rr) {
      sum[rr] += __shfl_xor(sum[rr], 1);
      sum[rr] += __shfl_xor(sum[rr], 2);
      sum[rr] += __shfl_xor(sum[rr], 4);
      sum[rr] += __shfl_xor(sum[rr], 8);
    }
    short* Ph = Pl + h * 8 * PP;
    if (kg < 2) {
#pragma unroll
      for (int rr = 0; rr < 4; ++rr) {
        float inv = 1.f / sum[rr];
        int tok = kg * 4 + rr;
#pragma unroll
        for (int nt = 0; nt < 7; ++nt)
          Ph[tok * PP + nt * 16 + lr] = f2bs(sc[nt][rr] * inv);
        Ph[tok * PP + 112 + lr] = 0;                  // pad cols 112..127 (R7)
        Ph[tok * PP + 128 + (lr & 3)] = 0;            // pad cols 128..131 (R7)
      }
    }
    __syncthreads();  // P visible (R7)
    // ---- PV: 8 MFMAs (R7 verbatim) ----
    f32x4 o2[2] = {f32x4{0, 0, 0, 0}, f32x4{0, 0, 0, 0}};
#pragma unroll
    for (int kt = 0; kt < 4; ++kt) {
      bf16x8 ap = ld8(Ph + (lr & 7) * PP + kt * 32 + kg * 8);
#pragma unroll
      for (int dt = 0; dt < 2; ++dt) {
        bf16x8 bv = ld8(Vt + (h * 32 + dt * 16 + lr) * VP + kt * 32 + kg * 8);
        o2[dt] = __builtin_amdgcn_mfma_f32_16x16x32_bf16(ap, bv, o2[dt], 0, 0, 0);
      }
    }
    if (kg < 2) {
#pragma unroll
      for (int dt = 0; dt < 2; ++dt)
#pragma unroll
        for (int rr = 0; rr < 4; ++rr)
          abuf[s * 8 + kg * 4 + rr][h * 32 + dt * 16 + lr] =
              __float2bfloat16(o2[dt][rr]);
    }
  }
  __syncthreads();  // abuf complete

  // ---- tail: proj+LN2 -> w1+res+LN3 -> w2+relu+LN4 -> w3+res -> NCHW ----
  int wid = tid >> 6;
  int mw = wid >> 1, nw = wid & 1;
  f32x4 acc[4];
  float x2f[4][4];

  auto gemm_lds = [&](const __hip_bfloat16* W) {
    bf16x8 af[4];
#pragma unroll
    for (int ks = 0; ks < 4; ++ks)
      af[ks] = *reinterpret_cast<const bf16x8*>(&abuf[mw * 16 + lr][ks * 32 + kg * 8]);
#pragma unroll
    for (int nf = 0; nf < 4; ++nf) {
      int o = nw * 64 + nf * 16 + lr;
      const __hip_bfloat16* wp = W + o * 128 + kg * 8;
      acc[nf] = f32x4{0, 0, 0, 0};
#pragma unroll
      for (int ks = 0; ks < 4; ++ks) {
        bf16x8 bfr = *reinterpret_cast<const bf16x8*>(wp + ks * 32);
        acc[nf] = __builtin_amdgcn_mfma_f32_16x16x32_bf16(af[ks], bfr, acc[nf], 0, 0, 0);
      }
    }
  };
  auto ln_store = [&](const float* g, const float* be) {
    float ps[4] = {0.f, 0.f, 0.f, 0.f}, pq[4] = {0.f, 0.f, 0.f, 0.f};
#pragma unroll
    for (int nf = 0; nf < 4; ++nf)
#pragma unroll
      for (int rr = 0; rr < 4; ++rr) {
        float v = acc[nf][rr];
        ps[rr] += v;
        pq[rr] += v * v;
      }
#pragma unroll
    for (int rr = 0; rr < 4; ++rr)
#pragma unroll
      for (int off = 1; off < 16; off <<= 1) {
        ps[rr] += __shfl_xor(ps[rr], off);
        pq[rr] += __shfl_xor(pq[rr], off);
      }
    if (lr == 0)
#pragma unroll
      for (int rr = 0; rr < 4; ++rr)
        red[mw][nw][kg * 4 + rr] = make_float2(ps[rr], pq[rr]);
    __syncthreads();
    float mu[4], rs[4];
#pragma unroll
    for (int rr = 0; rr < 4; ++rr) {
      float2 a0 = red[mw][0][kg * 4 + rr], a1 = red[mw][1][kg * 4 + rr];
      mu[rr] = (a0.x + a1.x) * (1.f / 128.f);
      float var = (a0.y + a1.y) * (1.f / 128.f) - mu[rr] * mu[rr];
      rs[rr] = rsqrtf(var + 1e-5f);
    }
#pragma unroll
    for (int nf = 0; nf < 4; ++nf) {
      int o = nw * 64 + nf * 16 + lr;
      float gv = g[o], bev = be[o];
#pragma unroll
      for (int rr = 0; rr < 4; ++rr)
        abuf[mw * 16 + kg * 4 + rr][o] =
            __float2bfloat16((acc[nf][rr] - mu[rr]) * rs[rr] * gv + bev);
    }
    __syncthreads();
  };

  // stage 1: proj + LN2 (A = attn output already in abuf)
  gemm_lds(wproj);
  __syncthreads();
#pragma unroll
  for (int nf = 0; nf < 4; ++nf) {
    float bv = bproj[nw * 64 + nf * 16 + lr];
#pragma unroll
    for (int rr = 0; rr < 4; ++rr) acc[nf][rr] += bv;
  }
  ln_store(g2, be2);

  // stage 2: w1 + residual r, save x2, LN3
  gemm_lds(w1);
  __syncthreads();
#pragma unroll
  for (int nf = 0; nf < 4; ++nf) {
    int o = nw * 64 + nf * 16 + lr;
    float bv = b1[o];
#pragma unroll
    for (int rr = 0; rr < 4; ++rr) {
      int m = m0 + mw * 16 + kg * 4 + rr;
      float v = acc[nf][rr] + bv + r[(size_t)m * 128 + o];
      x2f[nf][rr] = v;
      acc[nf][rr] = v;
    }
  }
  ln_store(g3, be3);

  // stage 3: w2 + relu + LN4
  gemm_lds(w2);
  __syncthreads();
#pragma unroll
  for (int nf = 0; nf < 4; ++nf) {
    float bv = b2[nw * 64 + nf * 16 + lr];
#pragma unroll
    for (int rr = 0; rr < 4; ++rr) acc[nf][rr] = fmaxf(acc[nf][rr] + bv, 0.f);
  }
  ln_store(g4, be4);

  // stage 4: w3 + x2 residual -> NCHW f32 out
  gemm_lds(w3);
#pragma unroll
  for (int nf = 0; nf < 4; ++nf) {
    int o = nw * 64 + nf * 16 + lr;
    float bv = b3[o];
#pragma unroll
    for (int rr = 0; rr < 4; ++rr) {
      int m = m0 + mw * 16 + kg * 4 + rr;
      float v = acc[nf][rr] + bv + x2f[nf][rr];
      int bb = m >> 12, hw = m & 4095;
      out[(size_t)bb * 524288 + o * 4096 + hw] = v;
    }
  }
}

// ---------------- launch ----------------
extern "C" void kernel_launch(void* const* d_in, const int* in_sizes, int n_in,
                              void* d_out, int out_size, void* d_ws,
                              size_t ws_size, hipStream_t stream) {
  const float* x = (const float*)d_in[0];
  const float* g1 = (const float*)d_in[1];
  const float* be1 = (const float*)d_in[2];
  const float* g2 = (const float*)d_in[3];
  const float* be2 = (const float*)d_in[4];
  const float* g3 = (const float*)d_in[5];
  const float* be3 = (const float*)d_in[6];
  const float* g4 = (const float*)d_in[7];
  const float* be4 = (const float*)d_in[8];
  const float* qkv_w = (const float*)d_in[9];
  const float* qkv_b = (const float*)d_in[10];
  const float* rpb = (const float*)d_in[11];
  const float* proj_w = (const float*)d_in[12];
  const float* proj_b = (const float*)d_in[13];
  const float* w1 = (const float*)d_in[14];
  const float* bl1 = (const float*)d_in[15];
  const float* w2 = (const float*)d_in[16];
  const float* bl2 = (const float*)d_in[17];
  const float* w3 = (const float*)d_in[18];
  const float* bl3 = (const float*)d_in[19];

  char* ws = (char*)d_ws;
  __hip_bfloat16* wb = (__hip_bfloat16*)ws;               // [65536] tail weights bf16
  float* r = (float*)(ws + 262144);                       // [8192][128] f32
  __hip_bfloat16* qkvb = (__hip_bfloat16*)(ws + 4456448); // [8192][384] bf16

  k_qkvcw<<<256, 256, 0, stream>>>(x, g1, be1, qkv_b, qkv_w, proj_w, w1, w2,
                                   w3, wb, r, qkvb);
  k_fuse2<<<256, 256, 0, stream>>>(qkvb, rpb, r, wb, proj_b, g2, be2, bl1, g3,
                                   be3, bl2, g4, be4, bl3, (float*)d_out);
}

// Round 11
// 56.583 us; speedup vs baseline: 1.1201x; 1.1201x over previous
//
#include <hip/hip_runtime.h>
#include <hip/hip_bf16.h>
#include <cstdint>

typedef short bf16x8 __attribute__((ext_vector_type(8)));
typedef float f32x4 __attribute__((ext_vector_type(4)));

// Problem constants: B=2, DIM=128, H=64, W=64, DH=32, HEADS=4, K=7
#define NTOK 8192
#define QSCALE 0.17677669529663687f

__device__ inline float b2f(short s) {
  return __uint_as_float(((unsigned)(unsigned short)s) << 16);
}
__device__ inline short f2bs(float x) {
  __hip_bfloat16 b = __float2bfloat16(x);
  return *reinterpret_cast<short*>(&b);
}
__device__ inline bf16x8 ld8(const short* p) {
  short4 lo = *reinterpret_cast<const short4*>(p);
  short4 hi = *reinterpret_cast<const short4*>(p + 4);
  bf16x8 r;
  r[0] = lo.x; r[1] = lo.y; r[2] = lo.z; r[3] = lo.w;
  r[4] = hi.x; r[5] = hi.y; r[6] = hi.z; r[7] = hi.w;
  return r;
}
__device__ inline bf16x8 cvt8(float4 a, float4 c) {
  bf16x8 r;
  r[0] = f2bs(a.x); r[1] = f2bs(a.y); r[2] = f2bs(a.z); r[3] = f2bs(a.w);
  r[4] = f2bs(c.x); r[5] = f2bs(c.y); r[6] = f2bs(c.z); r[7] = f2bs(c.w);
  return r;
}

// ---------------- K1: weight convert + NCHW->NHWC + LN1 + QKV GEMM (512 thr, 8 waves) ----------------
__global__ __launch_bounds__(512) void k_qkvcw(
    const float* __restrict__ x, const float* __restrict__ g,
    const float* __restrict__ be, const float* __restrict__ qkv_b,
    const float* __restrict__ qkv_w, const float* __restrict__ pw,
    const float* __restrict__ w1f, const float* __restrict__ w2f,
    const float* __restrict__ w3f, __hip_bfloat16* __restrict__ wb,
    float* __restrict__ r, __hip_bfloat16* __restrict__ qkvb) {
  __shared__ float xt[128][33];
  __shared__ __hip_bfloat16 at[32][136];
  int t = threadIdx.x;
  // --- prologue: convert tail weights (65536 elems over 256 blocks x 256 lanes) ---
  if (t < 256) {
    int ci = blockIdx.x * 256 + t;
    float cv;
    if (ci < 16384) cv = pw[ci];
    else if (ci < 32768) cv = w1f[ci - 16384];
    else if (ci < 49152) cv = w2f[ci - 32768];
    else cv = w3f[ci - 49152];
    wb[ci] = __float2bfloat16(cv);
  }
  int m0 = blockIdx.x * 32;
  int b = m0 >> 12;
  int p0 = m0 & 4095;
  const float* xb = x + (size_t)b * 524288;
  int tw = t & 31, th = t >> 5;  // th 0..15
#pragma unroll
  for (int i = 0; i < 8; ++i) {
    int c = i * 16 + th;
    xt[c][tw] = xb[c * 4096 + p0 + tw];
  }
  __syncthreads();
  int wid = t >> 6, lane = t & 63;  // wid 0..7
  float gg0 = g[lane], gg1 = g[lane + 64];
  float bb0 = be[lane], bb1 = be[lane + 64];
#pragma unroll
  for (int it = 0; it < 4; ++it) {
    int tt = wid * 4 + it;
    float v0 = xt[lane][tt], v1 = xt[lane + 64][tt];
    float s = v0 + v1, sq = v0 * v0 + v1 * v1;
#pragma unroll
    for (int off = 32; off; off >>= 1) {
      s += __shfl_xor(s, off);
      sq += __shfl_xor(sq, off);
    }
    float mu = s * (1.f / 128.f);
    float var = sq * (1.f / 128.f) - mu * mu;
    float rs = rsqrtf(var + 1e-5f);
    r[(size_t)(m0 + tt) * 128 + lane] = v0;
    r[(size_t)(m0 + tt) * 128 + 64 + lane] = v1;
    at[tt][lane] = __float2bfloat16((v0 - mu) * rs * gg0 + bb0);
    at[tt][lane + 64] = __float2bfloat16((v1 - mu) * rs * gg1 + bb1);
  }
  __syncthreads();
  // GEMM 32x384: 8 waves = 2(M) x 4(N of 96)
  int mw = wid >> 2, nwq = wid & 3;
  int lr = lane & 15, kg = lane >> 4;
  bf16x8 af[4];
#pragma unroll
  for (int ks = 0; ks < 4; ++ks)
    af[ks] = *reinterpret_cast<const bf16x8*>(&at[mw * 16 + lr][ks * 32 + kg * 8]);
  f32x4 acc[6];
#pragma unroll
  for (int nf = 0; nf < 6; ++nf) acc[nf] = f32x4{0, 0, 0, 0};
#pragma unroll
  for (int nf = 0; nf < 6; ++nf) {
    int o = nwq * 96 + nf * 16 + lr;
    const float* wp = qkv_w + o * 128 + kg * 8;
#pragma unroll
    for (int ks = 0; ks < 4; ++ks) {
      float4 wa = *reinterpret_cast<const float4*>(wp + ks * 32);
      float4 wc = *reinterpret_cast<const float4*>(wp + ks * 32 + 4);
      acc[nf] = __builtin_amdgcn_mfma_f32_16x16x32_bf16(af[ks], cvt8(wa, wc),
                                                        acc[nf], 0, 0, 0);
    }
  }
#pragma unroll
  for (int nf = 0; nf < 6; ++nf) {
    int o = nwq * 96 + nf * 16 + lr;
    float bv = qkv_b[o];
    float qs = (o < 128) ? QSCALE : 1.f;
#pragma unroll
    for (int rr = 0; rr < 4; ++rr) {
      int m = m0 + mw * 16 + kg * 4 + rr;
      qkvb[(size_t)m * 384 + o] = __float2bfloat16((acc[nf][rr] + bv) * qs);
    }
  }
}

// ---------------- K2: MFMA neighborhood attention (R7 verbatim) ----------------
#define NB 98
#define KP 132
#define VP 108
#define PP 132
__global__ __launch_bounds__(256) void k_attn3(
    const __hip_bfloat16* __restrict__ qkv, const float* __restrict__ rpb,
    __hip_bfloat16* __restrict__ ao) {
  __shared__ __align__(16) short smem[104 * KP + 128 * VP + 4 * 8 * PP];
  short* Kl = smem;
  short* Vt = smem + 104 * KP;
  short* Pl = Vt + 128 * VP;
  const short* qs = (const short*)qkv;
  int tid = threadIdx.x;
  int m0 = blockIdx.x * 8;
  int b = m0 >> 12, hq = (m0 >> 6) & 63, c0 = m0 & 63;
  int hs = min(max(hq - 3, 0), 57);
  int cs0 = min(max(c0 - 3, 0), 50);
#pragma unroll
  for (int it = 0; it < 7; ++it) {
    int idx = it * 256 + tid;
    if (idx < NB * 16) {
      int row = idx >> 4, sub = idx & 15;
      int rh = row / 14, rc = row - rh * 14;
      int tr = b * 4096 + (hs + rh) * 64 + min(cs0 + rc, 63);
      const short* src = qs + (size_t)tr * 384 + 128 + sub * 8;
      *(short4*)(Kl + row * KP + sub * 8) = *(const short4*)src;
      *(short4*)(Kl + row * KP + sub * 8 + 4) = *(const short4*)(src + 4);
      const short* sv = qs + (size_t)tr * 384 + 256 + sub * 8;
      short4 vlo = *(const short4*)sv;
      short4 vhi = *(const short4*)(sv + 4);
      int d0 = sub * 8;
      Vt[(d0 + 0) * VP + row] = vlo.x;
      Vt[(d0 + 1) * VP + row] = vlo.y;
      Vt[(d0 + 2) * VP + row] = vlo.z;
      Vt[(d0 + 3) * VP + row] = vlo.w;
      Vt[(d0 + 4) * VP + row] = vhi.x;
      Vt[(d0 + 5) * VP + row] = vhi.y;
      Vt[(d0 + 6) * VP + row] = vhi.z;
      Vt[(d0 + 7) * VP + row] = vhi.w;
    }
  }
  {
    int row = tid >> 1, half = tid & 1;
#pragma unroll
    for (int e = 0; e < 5; ++e) Vt[row * VP + NB + half * 5 + e] = 0;
  }
  __syncthreads();
  int h = tid >> 6, lane = tid & 63;
  int lr = lane & 15, kg = lane >> 4;
  int qrow = min(m0 + lr, NTOK - 1);
  bf16x8 aq = *reinterpret_cast<const bf16x8*>(qs + (size_t)qrow * 384 + h * 32 + kg * 8);
  f32x4 sc[7];
#pragma unroll
  for (int nt = 0; nt < 7; ++nt) {
    bf16x8 bk = ld8(Kl + (nt * 16 + lr) * KP + h * 32 + kg * 8);
    sc[nt] = __builtin_amdgcn_mfma_f32_16x16x32_bf16(aq, bk, f32x4{0, 0, 0, 0}, 0, 0, 0);
  }
  int offv[4], cmt[4];
#pragma unroll
  for (int rr = 0; rr < 4; ++rr) {
    int ct = c0 + kg * 4 + rr;
    int ws0 = min(max(ct - 3, 0), 57);
    offv[rr] = ws0 - cs0;
    cmt[rr] = cs0 + 6 - ct;
  }
  float mx[4] = {-3e38f, -3e38f, -3e38f, -3e38f};
#pragma unroll
  for (int nt = 0; nt < 7; ++nt) {
    int nbr = nt * 16 + lr;
    int rh = nbr / 14, rc = nbr - rh * 14;
    bool vn = nbr < NB;
    int ribase = h * 169 + (hs - hq + 6 + rh) * 13 + rc;
#pragma unroll
    for (int rr = 0; rr < 4; ++rr) {
      float v = -1e30f;
      if (vn && (unsigned)(rc - offv[rr]) < 7u) v = sc[nt][rr] + rpb[ribase + cmt[rr]];
      sc[nt][rr] = v;
      mx[rr] = fmaxf(mx[rr], v);
    }
  }
#pragma unroll
  for (int rr = 0; rr < 4; ++rr) {
    mx[rr] = fmaxf(mx[rr], __shfl_xor(mx[rr], 1));
    mx[rr] = fmaxf(mx[rr], __shfl_xor(mx[rr], 2));
    mx[rr] = fmaxf(mx[rr], __shfl_xor(mx[rr], 4));
    mx[rr] = fmaxf(mx[rr], __shfl_xor(mx[rr], 8));
  }
  float sum[4] = {0.f, 0.f, 0.f, 0.f};
#pragma unroll
  for (int nt = 0; nt < 7; ++nt)
#pragma unroll
    for (int rr = 0; rr < 4; ++rr) {
      float e = __expf(sc[nt][rr] - mx[rr]);
      sc[nt][rr] = e;
      sum[rr] += e;
    }
#pragma unroll
  for (int rr = 0; rr < 4; ++rr) {
    sum[rr] += __shfl_xor(sum[rr], 1);
    sum[rr] += __shfl_xor(sum[rr], 2);
    sum[rr] += __shfl_xor(sum[rr], 4);
    sum[rr] += __shfl_xor(sum[rr], 8);
  }
  short* Ph = Pl + h * 8 * PP;
  if (kg < 2) {
#pragma unroll
    for (int rr = 0; rr < 4; ++rr) {
      float inv = 1.f / sum[rr];
      int tok = kg * 4 + rr;
#pragma unroll
      for (int nt = 0; nt < 7; ++nt)
        Ph[tok * PP + nt * 16 + lr] = f2bs(sc[nt][rr] * inv);
      Ph[tok * PP + 112 + lr] = 0;
      Ph[tok * PP + 128 + (lr & 3)] = 0;
    }
  }
  __syncthreads();
  f32x4 o[2] = {f32x4{0, 0, 0, 0}, f32x4{0, 0, 0, 0}};
#pragma unroll
  for (int kt = 0; kt < 4; ++kt) {
    bf16x8 ap = ld8(Ph + (lr & 7) * PP + kt * 32 + kg * 8);
#pragma unroll
    for (int dt = 0; dt < 2; ++dt) {
      bf16x8 bv = ld8(Vt + (h * 32 + dt * 16 + lr) * VP + kt * 32 + kg * 8);
      o[dt] = __builtin_amdgcn_mfma_f32_16x16x32_bf16(ap, bv, o[dt], 0, 0, 0);
    }
  }
  if (kg < 2) {
#pragma unroll
    for (int dt = 0; dt < 2; ++dt)
#pragma unroll
      for (int rr = 0; rr < 4; ++rr) {
        int tok = kg * 4 + rr;
        ao[(size_t)(m0 + tok) * 128 + h * 32 + dt * 16 + lr] =
            __float2bfloat16(o[dt][rr]);
      }
  }
}

// ---------------- K3: fused tail, 512 thr (8 waves = 2M x 4N, nf=2) ----------------
__global__ __launch_bounds__(512) void k_tail(
    const __hip_bfloat16* __restrict__ ao, const float* __restrict__ r,
    const __hip_bfloat16* __restrict__ wb, const float* __restrict__ bproj,
    const float* __restrict__ g2, const float* __restrict__ be2,
    const float* __restrict__ b1,
    const float* __restrict__ g3, const float* __restrict__ be3,
    const float* __restrict__ b2,
    const float* __restrict__ g4, const float* __restrict__ be4,
    const float* __restrict__ b3, float* __restrict__ out) {
  __shared__ __hip_bfloat16 abuf[32][136];
  __shared__ float2 red[2][4][16];
  int t = threadIdx.x, wid = t >> 6, lane = t & 63;
  int mw = wid >> 2, nwq = wid & 3;
  int lr = lane & 15, kg = lane >> 4;
  int m0 = blockIdx.x * 32;
  const __hip_bfloat16* wproj = wb;
  const __hip_bfloat16* w1 = wb + 16384;
  const __hip_bfloat16* w2 = wb + 32768;
  const __hip_bfloat16* w3 = wb + 49152;
  f32x4 acc[2];
  float x2f[2][4];

  auto gemm_glob = [&](const __hip_bfloat16* Aglob, const __hip_bfloat16* W) {
    bf16x8 af[4];
#pragma unroll
    for (int ks = 0; ks < 4; ++ks)
      af[ks] = *reinterpret_cast<const bf16x8*>(Aglob + (mw * 16 + lr) * 128 + ks * 32 + kg * 8);
#pragma unroll
    for (int nf = 0; nf < 2; ++nf) {
      int o = nwq * 32 + nf * 16 + lr;
      const __hip_bfloat16* wp = W + o * 128 + kg * 8;
      acc[nf] = f32x4{0, 0, 0, 0};
#pragma unroll
      for (int ks = 0; ks < 4; ++ks) {
        bf16x8 bfr = *reinterpret_cast<const bf16x8*>(wp + ks * 32);
        acc[nf] = __builtin_amdgcn_mfma_f32_16x16x32_bf16(af[ks], bfr, acc[nf], 0, 0, 0);
      }
    }
  };
  auto gemm_lds = [&](const __hip_bfloat16* W) {
    bf16x8 af[4];
#pragma unroll
    for (int ks = 0; ks < 4; ++ks)
      af[ks] = *reinterpret_cast<const bf16x8*>(&abuf[mw * 16 + lr][ks * 32 + kg * 8]);
#pragma unroll
    for (int nf = 0; nf < 2; ++nf) {
      int o = nwq * 32 + nf * 16 + lr;
      const __hip_bfloat16* wp = W + o * 128 + kg * 8;
      acc[nf] = f32x4{0, 0, 0, 0};
#pragma unroll
      for (int ks = 0; ks < 4; ++ks) {
        bf16x8 bfr = *reinterpret_cast<const bf16x8*>(wp + ks * 32);
        acc[nf] = __builtin_amdgcn_mfma_f32_16x16x32_bf16(af[ks], bfr, acc[nf], 0, 0, 0);
      }
    }
  };
  auto ln_store = [&](const float* g, const float* be) {
    float ps[4] = {0.f, 0.f, 0.f, 0.f}, pq[4] = {0.f, 0.f, 0.f, 0.f};
#pragma unroll
    for (int nf = 0; nf < 2; ++nf)
#pragma unroll
      for (int rr = 0; rr < 4; ++rr) {
        float v = acc[nf][rr];
        ps[rr] += v;
        pq[rr] += v * v;
      }
#pragma unroll
    for (int rr = 0; rr < 4; ++rr)
#pragma unroll
      for (int off = 1; off < 16; off <<= 1) {
        ps[rr] += __shfl_xor(ps[rr], off);
        pq[rr] += __shfl_xor(pq[rr], off);
      }
    if (lr == 0)
#pragma unroll
      for (int rr = 0; rr < 4; ++rr)
        red[mw][nwq][kg * 4 + rr] = make_float2(ps[rr], pq[rr]);
    __syncthreads();
    float mu[4], rs[4];
#pragma unroll
    for (int rr = 0; rr < 4; ++rr) {
      int r16 = kg * 4 + rr;
      float2 a0 = red[mw][0][r16], a1 = red[mw][1][r16];
      float2 a2 = red[mw][2][r16], a3 = red[mw][3][r16];
      float ssum = a0.x + a1.x + a2.x + a3.x;
      float qsum = a0.y + a1.y + a2.y + a3.y;
      mu[rr] = ssum * (1.f / 128.f);
      float var = qsum * (1.f / 128.f) - mu[rr] * mu[rr];
      rs[rr] = rsqrtf(var + 1e-5f);
    }
#pragma unroll
    for (int nf = 0; nf < 2; ++nf) {
      int o = nwq * 32 + nf * 16 + lr;
      float gv = g[o], bev = be[o];
#pragma unroll
      for (int rr = 0; rr < 4; ++rr)
        abuf[mw * 16 + kg * 4 + rr][o] =
            __float2bfloat16((acc[nf][rr] - mu[rr]) * rs[rr] * gv + bev);
    }
    __syncthreads();
  };

  // stage 1: proj + LN2 (A = attn output from global)
  gemm_glob(ao + (size_t)m0 * 128, wproj);
#pragma unroll
  for (int nf = 0; nf < 2; ++nf) {
    float bv = bproj[nwq * 32 + nf * 16 + lr];
#pragma unroll
    for (int rr = 0; rr < 4; ++rr) acc[nf][rr] += bv;
  }
  ln_store(g2, be2);

  // stage 2: w1 + residual r, save x2, LN3
  gemm_lds(w1);
  __syncthreads();  // all abuf frag-reads done before ln_store rewrites abuf
#pragma unroll
  for (int nf = 0; nf < 2; ++nf) {
    int o = nwq * 32 + nf * 16 + lr;
    float bv = b1[o];
#pragma unroll
    for (int rr = 0; rr < 4; ++rr) {
      int m = m0 + mw * 16 + kg * 4 + rr;
      float v = acc[nf][rr] + bv + r[(size_t)m * 128 + o];
      x2f[nf][rr] = v;
      acc[nf][rr] = v;
    }
  }
  ln_store(g3, be3);

  // stage 3: w2 + relu + LN4
  gemm_lds(w2);
  __syncthreads();
#pragma unroll
  for (int nf = 0; nf < 2; ++nf) {
    float bv = b2[nwq * 32 + nf * 16 + lr];
#pragma unroll
    for (int rr = 0; rr < 4; ++rr) acc[nf][rr] = fmaxf(acc[nf][rr] + bv, 0.f);
  }
  ln_store(g4, be4);

  // stage 4: w3 + x2 residual -> NCHW f32 out
  gemm_lds(w3);
#pragma unroll
  for (int nf = 0; nf < 2; ++nf) {
    int o = nwq * 32 + nf * 16 + lr;
    float bv = b3[o];
#pragma unroll
    for (int rr = 0; rr < 4; ++rr) {
      int m = m0 + mw * 16 + kg * 4 + rr;
      float v = acc[nf][rr] + bv + x2f[nf][rr];
      int bb = m >> 12, hw = m & 4095;
      out[(size_t)bb * 524288 + o * 4096 + hw] = v;
    }
  }
}

// ---------------- launch ----------------
extern "C" void kernel_launch(void* const* d_in, const int* in_sizes, int n_in,
                              void* d_out, int out_size, void* d_ws,
                              size_t ws_size, hipStream_t stream) {
  const float* x = (const float*)d_in[0];
  const float* g1 = (const float*)d_in[1];
  const float* be1 = (const float*)d_in[2];
  const float* g2 = (const float*)d_in[3];
  const float* be2 = (const float*)d_in[4];
  const float* g3 = (const float*)d_in[5];
  const float* be3 = (const float*)d_in[6];
  const float* g4 = (const float*)d_in[7];
  const float* be4 = (const float*)d_in[8];
  const float* qkv_w = (const float*)d_in[9];
  const float* qkv_b = (const float*)d_in[10];
  const float* rpb = (const float*)d_in[11];
  const float* proj_w = (const float*)d_in[12];
  const float* proj_b = (const float*)d_in[13];
  const float* w1 = (const float*)d_in[14];
  const float* bl1 = (const float*)d_in[15];
  const float* w2 = (const float*)d_in[16];
  const float* bl2 = (const float*)d_in[17];
  const float* w3 = (const float*)d_in[18];
  const float* bl3 = (const float*)d_in[19];

  char* ws = (char*)d_ws;
  __hip_bfloat16* wb = (__hip_bfloat16*)ws;               // [65536] tail weights bf16
  float* r = (float*)(ws + 262144);                       // [8192][128] f32
  __hip_bfloat16* qkvb = (__hip_bfloat16*)(ws + 4456448); // [8192][384] bf16
  __hip_bfloat16* ao = (__hip_bfloat16*)(ws + 10747904);  // [8192][128] bf16

  k_qkvcw<<<256, 512, 0, stream>>>(x, g1, be1, qkv_b, qkv_w, proj_w, w1, w2,
                                   w3, wb, r, qkvb);
  k_attn3<<<1024, 256, 0, stream>>>(qkvb, rpb, ao);
  k_tail<<<256, 512, 0, stream>>>(ao, r, wb, proj_b, g2, be2, bl1, g3, be3,
                                  bl2, g4, be4, bl3, (float*)d_out);
}

// Round 13
// 51.098 us; speedup vs baseline: 1.2403x; 1.1073x over previous
//
#include <hip/hip_runtime.h>
#include <hip/hip_bf16.h>
#include <cstdint>

typedef short bf16x8 __attribute__((ext_vector_type(8)));
typedef float f32x4 __attribute__((ext_vector_type(4)));

// Problem constants: B=2, DIM=128, H=64, W=64, DH=32, HEADS=4, K=7
#define NTOK 8192
#define QSCALE 0.17677669529663687f

__device__ inline float b2f(short s) {
  return __uint_as_float(((unsigned)(unsigned short)s) << 16);
}
__device__ inline short f2bs(float x) {
  __hip_bfloat16 b = __float2bfloat16(x);
  return *reinterpret_cast<short*>(&b);
}
__device__ inline bf16x8 ld8(const short* p) {
  short4 lo = *reinterpret_cast<const short4*>(p);
  short4 hi = *reinterpret_cast<const short4*>(p + 4);
  bf16x8 r;
  r[0] = lo.x; r[1] = lo.y; r[2] = lo.z; r[3] = lo.w;
  r[4] = hi.x; r[5] = hi.y; r[6] = hi.z; r[7] = hi.w;
  return r;
}
__device__ inline bf16x8 cvt8(float4 a, float4 c) {
  bf16x8 r;
  r[0] = f2bs(a.x); r[1] = f2bs(a.y); r[2] = f2bs(a.z); r[3] = f2bs(a.w);
  r[4] = f2bs(c.x); r[5] = f2bs(c.y); r[6] = f2bs(c.z); r[7] = f2bs(c.w);
  return r;
}

// ---------------- K1: weight convert + NCHW->NHWC + LN1 + QKV GEMM (512 thr) ----------------
__global__ __launch_bounds__(512) void k_qkvcw(
    const float* __restrict__ x, const float* __restrict__ g,
    const float* __restrict__ be, const float* __restrict__ qkv_b,
    const float* __restrict__ qkv_w, const float* __restrict__ pw,
    const float* __restrict__ w1f, const float* __restrict__ w2f,
    const float* __restrict__ w3f, __hip_bfloat16* __restrict__ wb,
    float* __restrict__ r, __hip_bfloat16* __restrict__ qkvb) {
  __shared__ float xt[128][33];
  __shared__ __hip_bfloat16 at[32][136];
  int t = threadIdx.x;
  if (t < 256) {
    int ci = blockIdx.x * 256 + t;
    float cv;
    if (ci < 16384) cv = pw[ci];
    else if (ci < 32768) cv = w1f[ci - 16384];
    else if (ci < 49152) cv = w2f[ci - 32768];
    else cv = w3f[ci - 49152];
    wb[ci] = __float2bfloat16(cv);
  }
  int m0 = blockIdx.x * 32;
  int b = m0 >> 12;
  int p0 = m0 & 4095;
  const float* xb = x + (size_t)b * 524288;
  int tw = t & 31, th = t >> 5;
#pragma unroll
  for (int i = 0; i < 8; ++i) {
    int c = i * 16 + th;
    xt[c][tw] = xb[c * 4096 + p0 + tw];
  }
  __syncthreads();
  int wid = t >> 6, lane = t & 63;
  float gg0 = g[lane], gg1 = g[lane + 64];
  float bb0 = be[lane], bb1 = be[lane + 64];
#pragma unroll
  for (int it = 0; it < 4; ++it) {
    int tt = wid * 4 + it;
    float v0 = xt[lane][tt], v1 = xt[lane + 64][tt];
    float s = v0 + v1, sq = v0 * v0 + v1 * v1;
#pragma unroll
    for (int off = 32; off; off >>= 1) {
      s += __shfl_xor(s, off);
      sq += __shfl_xor(sq, off);
    }
    float mu = s * (1.f / 128.f);
    float var = sq * (1.f / 128.f) - mu * mu;
    float rs = rsqrtf(var + 1e-5f);
    r[(size_t)(m0 + tt) * 128 + lane] = v0;
    r[(size_t)(m0 + tt) * 128 + 64 + lane] = v1;
    at[tt][lane] = __float2bfloat16((v0 - mu) * rs * gg0 + bb0);
    at[tt][lane + 64] = __float2bfloat16((v1 - mu) * rs * gg1 + bb1);
  }
  __syncthreads();
  int mw = wid >> 2, nwq = wid & 3;
  int lr = lane & 15, kg = lane >> 4;
  bf16x8 af[4];
#pragma unroll
  for (int ks = 0; ks < 4; ++ks)
    af[ks] = *reinterpret_cast<const bf16x8*>(&at[mw * 16 + lr][ks * 32 + kg * 8]);
  f32x4 acc[6];
#pragma unroll
  for (int nf = 0; nf < 6; ++nf) acc[nf] = f32x4{0, 0, 0, 0};
#pragma unroll
  for (int nf = 0; nf < 6; ++nf) {
    int o = nwq * 96 + nf * 16 + lr;
    const float* wp = qkv_w + o * 128 + kg * 8;
#pragma unroll
    for (int ks = 0; ks < 4; ++ks) {
      float4 wa = *reinterpret_cast<const float4*>(wp + ks * 32);
      float4 wc = *reinterpret_cast<const float4*>(wp + ks * 32 + 4);
      acc[nf] = __builtin_amdgcn_mfma_f32_16x16x32_bf16(af[ks], cvt8(wa, wc),
                                                        acc[nf], 0, 0, 0);
    }
  }
#pragma unroll
  for (int nf = 0; nf < 6; ++nf) {
    int o = nwq * 96 + nf * 16 + lr;
    float bv = qkv_b[o];
    float qs = (o < 128) ? QSCALE : 1.f;
#pragma unroll
    for (int rr = 0; rr < 4; ++rr) {
      int m = m0 + mw * 16 + kg * 4 + rr;
      qkvb[(size_t)m * 384 + o] = __float2bfloat16((acc[nf][rr] + bv) * qs);
    }
  }
}

// ---------------- K2: MFMA neighborhood attention, K-from-global, V staged ----------------
// LDS 35.3KB -> 4 blocks/CU (was 63.5KB/2). Vt then Pl in ONE smem[] so the
// known PV row-127 k=108..127 overflow lands in Pl (always written before the
// pre-PV barrier; finite; x P=0) — the R8/R9 NaN was separate-array layout
// placing uninitialized LDS there instead.
#define NB 98
#define VP 108
#define PP 132
__global__ __launch_bounds__(256) void k_attn4(
    const __hip_bfloat16* __restrict__ qkv, const float* __restrict__ rpb,
    __hip_bfloat16* __restrict__ ao) {
  __shared__ __align__(16) short smem[128 * VP + 4 * 8 * PP];
  short* Vt = smem;             // [128][VP]
  short* Pl = smem + 128 * VP;  // [4][8][PP]
  const short* qs = (const short*)qkv;
  int tid = threadIdx.x;
  // bijective XCD swizzle (1024 blocks % 8 == 0): contiguous strips per XCD L2
  int bid = blockIdx.x;
  int swz = (bid & 7) * 128 + (bid >> 3);
  int m0 = swz * 8;
  int b = m0 >> 12, hq = (m0 >> 6) & 63, c0 = m0 & 63;
  int hs = min(max(hq - 3, 0), 57);
  int cs0 = min(max(c0 - 3, 0), 50);
  // ---- stage V (transposed) only ----
#pragma unroll
  for (int it = 0; it < 7; ++it) {
    int idx = it * 256 + tid;
    if (idx < NB * 16) {
      int row = idx >> 4, sub = idx & 15;
      int rh = row / 14, rc = row - rh * 14;
      int tr = b * 4096 + (hs + rh) * 64 + min(cs0 + rc, 63);
      const short* sv = qs + (size_t)tr * 384 + 256 + sub * 8;
      short4 vlo = *(const short4*)sv;
      short4 vhi = *(const short4*)(sv + 4);
      int d0 = sub * 8;
      Vt[(d0 + 0) * VP + row] = vlo.x;
      Vt[(d0 + 1) * VP + row] = vlo.y;
      Vt[(d0 + 2) * VP + row] = vlo.z;
      Vt[(d0 + 3) * VP + row] = vlo.w;
      Vt[(d0 + 4) * VP + row] = vhi.x;
      Vt[(d0 + 5) * VP + row] = vhi.y;
      Vt[(d0 + 6) * VP + row] = vhi.z;
      Vt[(d0 + 7) * VP + row] = vhi.w;
    }
  }
  {  // zero Vt pad cols 98..107
    int row = tid >> 1, half = tid & 1;
#pragma unroll
    for (int e = 0; e < 5; ++e) Vt[row * VP + NB + half * 5 + e] = 0;
  }
  int h = tid >> 6, lane = tid & 63;
  int lr = lane & 15, kg = lane >> 4;
  // ---- QK^T: 7 MFMAs, B-fragments straight from global (L2-hot) ----
  int qrow = min(m0 + lr, NTOK - 1);
  bf16x8 aq = *reinterpret_cast<const bf16x8*>(qs + (size_t)qrow * 384 + h * 32 + kg * 8);
  f32x4 sc[7];
#pragma unroll
  for (int nt = 0; nt < 7; ++nt) {
    int nbr = nt * 16 + lr;
    int rw = min(nbr, NB - 1);
    int rh = rw / 14, rc = rw - rh * 14;
    int tn = b * 4096 + (hs + rh) * 64 + min(cs0 + rc, 63);
    bf16x8 bk = *reinterpret_cast<const bf16x8*>(qs + (size_t)tn * 384 + 128 + h * 32 + kg * 8);
    sc[nt] = __builtin_amdgcn_mfma_f32_16x16x32_bf16(aq, bk, f32x4{0, 0, 0, 0}, 0, 0, 0);
  }
  // ---- rpb + mask + softmax (row = token on kg, col = neighbor on lr) ----
  int offv[4], cmt[4];
#pragma unroll
  for (int rr = 0; rr < 4; ++rr) {
    int ct = c0 + kg * 4 + rr;
    int ws0 = min(max(ct - 3, 0), 57);
    offv[rr] = ws0 - cs0;
    cmt[rr] = cs0 + 6 - ct;
  }
  float mx[4] = {-3e38f, -3e38f, -3e38f, -3e38f};
#pragma unroll
  for (int nt = 0; nt < 7; ++nt) {
    int nbr = nt * 16 + lr;
    int rh = nbr / 14, rc = nbr - rh * 14;
    bool vn = nbr < NB;
    int ribase = h * 169 + (hs - hq + 6 + rh) * 13 + rc;
#pragma unroll
    for (int rr = 0; rr < 4; ++rr) {
      float v = -1e30f;
      if (vn && (unsigned)(rc - offv[rr]) < 7u) v = sc[nt][rr] + rpb[ribase + cmt[rr]];
      sc[nt][rr] = v;
      mx[rr] = fmaxf(mx[rr], v);
    }
  }
#pragma unroll
  for (int rr = 0; rr < 4; ++rr) {
    mx[rr] = fmaxf(mx[rr], __shfl_xor(mx[rr], 1));
    mx[rr] = fmaxf(mx[rr], __shfl_xor(mx[rr], 2));
    mx[rr] = fmaxf(mx[rr], __shfl_xor(mx[rr], 4));
    mx[rr] = fmaxf(mx[rr], __shfl_xor(mx[rr], 8));
  }
  float sum[4] = {0.f, 0.f, 0.f, 0.f};
#pragma unroll
  for (int nt = 0; nt < 7; ++nt)
#pragma unroll
    for (int rr = 0; rr < 4; ++rr) {
      float e = __expf(sc[nt][rr] - mx[rr]);
      sc[nt][rr] = e;
      sum[rr] += e;
    }
#pragma unroll
  for (int rr = 0; rr < 4; ++rr) {
    sum[rr] += __shfl_xor(sum[rr], 1);
    sum[rr] += __shfl_xor(sum[rr], 2);
    sum[rr] += __shfl_xor(sum[rr], 4);
    sum[rr] += __shfl_xor(sum[rr], 8);
  }
  short* Ph = Pl + h * 8 * PP;
  if (kg < 2) {
#pragma unroll
    for (int rr = 0; rr < 4; ++rr) {
      float inv = 1.f / sum[rr];
      int tok = kg * 4 + rr;
#pragma unroll
      for (int nt = 0; nt < 7; ++nt)
        Ph[tok * PP + nt * 16 + lr] = f2bs(sc[nt][rr] * inv);
      Ph[tok * PP + 112 + lr] = 0;
      Ph[tok * PP + 128 + (lr & 3)] = 0;
    }
  }
  __syncthreads();  // Vt staged + P visible
  // ---- PV: 8 MFMAs ----
  f32x4 o[2] = {f32x4{0, 0, 0, 0}, f32x4{0, 0, 0, 0}};
#pragma unroll
  for (int kt = 0; kt < 4; ++kt) {
    bf16x8 ap = ld8(Ph + (lr & 7) * PP + kt * 32 + kg * 8);
#pragma unroll
    for (int dt = 0; dt < 2; ++dt) {
      bf16x8 bv = ld8(Vt + (h * 32 + dt * 16 + lr) * VP + kt * 32 + kg * 8);
      o[dt] = __builtin_amdgcn_mfma_f32_16x16x32_bf16(ap, bv, o[dt], 0, 0, 0);
    }
  }
  if (kg < 2) {
#pragma unroll
    for (int dt = 0; dt < 2; ++dt)
#pragma unroll
      for (int rr = 0; rr < 4; ++rr) {
        int tok = kg * 4 + rr;
        ao[(size_t)(m0 + tok) * 128 + h * 32 + dt * 16 + lr] =
            __float2bfloat16(o[dt][rr]);
      }
  }
}

// ---------------- K3: fused tail, 512 thr (8 waves = 2M x 4N, nf=2) ----------------
__global__ __launch_bounds__(512) void k_tail(
    const __hip_bfloat16* __restrict__ ao, const float* __restrict__ r,
    const __hip_bfloat16* __restrict__ wb, const float* __restrict__ bproj,
    const float* __restrict__ g2, const float* __restrict__ be2,
    const float* __restrict__ b1,
    const float* __restrict__ g3, const float* __restrict__ be3,
    const float* __restrict__ b2,
    const float* __restrict__ g4, const float* __restrict__ be4,
    const float* __restrict__ b3, float* __restrict__ out) {
  __shared__ __hip_bfloat16 abuf[32][136];
  __shared__ float2 red[2][4][16];
  int t = threadIdx.x, wid = t >> 6, lane = t & 63;
  int mw = wid >> 2, nwq = wid & 3;
  int lr = lane & 15, kg = lane >> 4;
  int m0 = blockIdx.x * 32;
  const __hip_bfloat16* wproj = wb;
  const __hip_bfloat16* w1 = wb + 16384;
  const __hip_bfloat16* w2 = wb + 32768;
  const __hip_bfloat16* w3 = wb + 49152;
  f32x4 acc[2];
  float x2f[2][4];

  auto gemm_glob = [&](const __hip_bfloat16* Aglob, const __hip_bfloat16* W) {
    bf16x8 af[4];
#pragma unroll
    for (int ks = 0; ks < 4; ++ks)
      af[ks] = *reinterpret_cast<const bf16x8*>(Aglob + (mw * 16 + lr) * 128 + ks * 32 + kg * 8);
#pragma unroll
    for (int nf = 0; nf < 2; ++nf) {
      int o = nwq * 32 + nf * 16 + lr;
      const __hip_bfloat16* wp = W + o * 128 + kg * 8;
      acc[nf] = f32x4{0, 0, 0, 0};
#pragma unroll
      for (int ks = 0; ks < 4; ++ks) {
        bf16x8 bfr = *reinterpret_cast<const bf16x8*>(wp + ks * 32);
        acc[nf] = __builtin_amdgcn_mfma_f32_16x16x32_bf16(af[ks], bfr, acc[nf], 0, 0, 0);
      }
    }
  };
  auto gemm_lds = [&](const __hip_bfloat16* W) {
    bf16x8 af[4];
#pragma unroll
    for (int ks = 0; ks < 4; ++ks)
      af[ks] = *reinterpret_cast<const bf16x8*>(&abuf[mw * 16 + lr][ks * 32 + kg * 8]);
#pragma unroll
    for (int nf = 0; nf < 2; ++nf) {
      int o = nwq * 32 + nf * 16 + lr;
      const __hip_bfloat16* wp = W + o * 128 + kg * 8;
      acc[nf] = f32x4{0, 0, 0, 0};
#pragma unroll
      for (int ks = 0; ks < 4; ++ks) {
        bf16x8 bfr = *reinterpret_cast<const bf16x8*>(wp + ks * 32);
        acc[nf] = __builtin_amdgcn_mfma_f32_16x16x32_bf16(af[ks], bfr, acc[nf], 0, 0, 0);
      }
    }
  };
  auto ln_store = [&](const float* g, const float* be) {
    float ps[4] = {0.f, 0.f, 0.f, 0.f}, pq[4] = {0.f, 0.f, 0.f, 0.f};
#pragma unroll
    for (int nf = 0; nf < 2; ++nf)
#pragma unroll
      for (int rr = 0; rr < 4; ++rr) {
        float v = acc[nf][rr];
        ps[rr] += v;
        pq[rr] += v * v;
      }
#pragma unroll
    for (int rr = 0; rr < 4; ++rr)
#pragma unroll
      for (int off = 1; off < 16; off <<= 1) {
        ps[rr] += __shfl_xor(ps[rr], off);
        pq[rr] += __shfl_xor(pq[rr], off);
      }
    if (lr == 0)
#pragma unroll
      for (int rr = 0; rr < 4; ++rr)
        red[mw][nwq][kg * 4 + rr] = make_float2(ps[rr], pq[rr]);
    __syncthreads();
    float mu[4], rs[4];
#pragma unroll
    for (int rr = 0; rr < 4; ++rr) {
      int r16 = kg * 4 + rr;
      float2 a0 = red[mw][0][r16], a1 = red[mw][1][r16];
      float2 a2 = red[mw][2][r16], a3 = red[mw][3][r16];
      float ssum = a0.x + a1.x + a2.x + a3.x;
      float qsum = a0.y + a1.y + a2.y + a3.y;
      mu[rr] = ssum * (1.f / 128.f);
      float var = qsum * (1.f / 128.f) - mu[rr] * mu[rr];
      rs[rr] = rsqrtf(var + 1e-5f);
    }
#pragma unroll
    for (int nf = 0; nf < 2; ++nf) {
      int o = nwq * 32 + nf * 16 + lr;
      float gv = g[o], bev = be[o];
#pragma unroll
      for (int rr = 0; rr < 4; ++rr)
        abuf[mw * 16 + kg * 4 + rr][o] =
            __float2bfloat16((acc[nf][rr] - mu[rr]) * rs[rr] * gv + bev);
    }
    __syncthreads();
  };

  // stage 1: proj + LN2
  gemm_glob(ao + (size_t)m0 * 128, wproj);
#pragma unroll
  for (int nf = 0; nf < 2; ++nf) {
    float bv = bproj[nwq * 32 + nf * 16 + lr];
#pragma unroll
    for (int rr = 0; rr < 4; ++rr) acc[nf][rr] += bv;
  }
  ln_store(g2, be2);

  // stage 2: w1 + residual r, save x2, LN3
  gemm_lds(w1);
  __syncthreads();
#pragma unroll
  for (int nf = 0; nf < 2; ++nf) {
    int o = nwq * 32 + nf * 16 + lr;
    float bv = b1[o];
#pragma unroll
    for (int rr = 0; rr < 4; ++rr) {
      int m = m0 + mw * 16 + kg * 4 + rr;
      float v = acc[nf][rr] + bv + r[(size_t)m * 128 + o];
      x2f[nf][rr] = v;
      acc[nf][rr] = v;
    }
  }
  ln_store(g3, be3);

  // stage 3: w2 + relu + LN4
  gemm_lds(w2);
  __syncthreads();
#pragma unroll
  for (int nf = 0; nf < 2; ++nf) {
    float bv = b2[nwq * 32 + nf * 16 + lr];
#pragma unroll
    for (int rr = 0; rr < 4; ++rr) acc[nf][rr] = fmaxf(acc[nf][rr] + bv, 0.f);
  }
  ln_store(g4, be4);

  // stage 4: w3 + x2 residual -> NCHW f32 out
  gemm_lds(w3);
#pragma unroll
  for (int nf = 0; nf < 2; ++nf) {
    int o = nwq * 32 + nf * 16 + lr;
    float bv = b3[o];
#pragma unroll
    for (int rr = 0; rr < 4; ++rr) {
      int m = m0 + mw * 16 + kg * 4 + rr;
      float v = acc[nf][rr] + bv + x2f[nf][rr];
      int bb = m >> 12, hw = m & 4095;
      out[(size_t)bb * 524288 + o * 4096 + hw] = v;
    }
  }
}

// ---------------- launch ----------------
extern "C" void kernel_launch(void* const* d_in, const int* in_sizes, int n_in,
                              void* d_out, int out_size, void* d_ws,
                              size_t ws_size, hipStream_t stream) {
  const float* x = (const float*)d_in[0];
  const float* g1 = (const float*)d_in[1];
  const float* be1 = (const float*)d_in[2];
  const float* g2 = (const float*)d_in[3];
  const float* be2 = (const float*)d_in[4];
  const float* g3 = (const float*)d_in[5];
  const float* be3 = (const float*)d_in[6];
  const float* g4 = (const float*)d_in[7];
  const float* be4 = (const float*)d_in[8];
  const float* qkv_w = (const float*)d_in[9];
  const float* qkv_b = (const float*)d_in[10];
  const float* rpb = (const float*)d_in[11];
  const float* proj_w = (const float*)d_in[12];
  const float* proj_b = (const float*)d_in[13];
  const float* w1 = (const float*)d_in[14];
  const float* bl1 = (const float*)d_in[15];
  const float* w2 = (const float*)d_in[16];
  const float* bl2 = (const float*)d_in[17];
  const float* w3 = (const float*)d_in[18];
  const float* bl3 = (const float*)d_in[19];

  char* ws = (char*)d_ws;
  __hip_bfloat16* wb = (__hip_bfloat16*)ws;               // [65536] tail weights bf16
  float* r = (float*)(ws + 262144);                       // [8192][128] f32
  __hip_bfloat16* qkvb = (__hip_bfloat16*)(ws + 4456448); // [8192][384] bf16
  __hip_bfloat16* ao = (__hip_bfloat16*)(ws + 10747904);  // [8192][128] bf16

  k_qkvcw<<<256, 512, 0, stream>>>(x, g1, be1, qkv_b, qkv_w, proj_w, w1, w2,
                                   w3, wb, r, qkvb);
  k_attn4<<<1024, 256, 0, stream>>>(qkvb, rpb, ao);
  k_tail<<<256, 512, 0, stream>>>(ao, r, wb, proj_b, g2, be2, bl1, g3, be3,
                                  bl2, g4, be4, bl3, (float*)d_out);
}

// Round 15
// 50.936 us; speedup vs baseline: 1.2443x; 1.0032x over previous
//
#include <hip/hip_runtime.h>
#include <hip/hip_bf16.h>
#include <cstdint>

typedef short bf16x8 __attribute__((ext_vector_type(8)));
typedef float f32x4 __attribute__((ext_vector_type(4)));

// Problem constants: B=2, DIM=128, H=64, W=64, DH=32, HEADS=4, K=7
#define NTOK 8192
#define QSCALE 0.17677669529663687f

__device__ inline float b2f(short s) {
  return __uint_as_float(((unsigned)(unsigned short)s) << 16);
}
__device__ inline short f2bs(float x) {
  __hip_bfloat16 b = __float2bfloat16(x);
  return *reinterpret_cast<short*>(&b);
}
__device__ inline bf16x8 ld8(const short* p) {
  short4 lo = *reinterpret_cast<const short4*>(p);
  short4 hi = *reinterpret_cast<const short4*>(p + 4);
  bf16x8 r;
  r[0] = lo.x; r[1] = lo.y; r[2] = lo.z; r[3] = lo.w;
  r[4] = hi.x; r[5] = hi.y; r[6] = hi.z; r[7] = hi.w;
  return r;
}
__device__ inline bf16x8 cvt8(float4 a, float4 c) {
  bf16x8 r;
  r[0] = f2bs(a.x); r[1] = f2bs(a.y); r[2] = f2bs(a.z); r[3] = f2bs(a.w);
  r[4] = f2bs(c.x); r[5] = f2bs(c.y); r[6] = f2bs(c.z); r[7] = f2bs(c.w);
  return r;
}

// ---------------- K1: weight convert + NCHW->NHWC + LN1 + QKV GEMM (512 thr) ----------------
__global__ __launch_bounds__(512) void k_qkvcw(
    const float* __restrict__ x, const float* __restrict__ g,
    const float* __restrict__ be, const float* __restrict__ qkv_b,
    const float* __restrict__ qkv_w, const float* __restrict__ pw,
    const float* __restrict__ w1f, const float* __restrict__ w2f,
    const float* __restrict__ w3f, __hip_bfloat16* __restrict__ wb,
    float* __restrict__ r, __hip_bfloat16* __restrict__ qkvb) {
  __shared__ float xt[128][33];
  __shared__ __hip_bfloat16 at[32][136];
  int t = threadIdx.x;
  if (t < 256) {
    int ci = blockIdx.x * 256 + t;
    float cv;
    if (ci < 16384) cv = pw[ci];
    else if (ci < 32768) cv = w1f[ci - 16384];
    else if (ci < 49152) cv = w2f[ci - 32768];
    else cv = w3f[ci - 49152];
    wb[ci] = __float2bfloat16(cv);
  }
  int m0 = blockIdx.x * 32;
  int b = m0 >> 12;
  int p0 = m0 & 4095;
  const float* xb = x + (size_t)b * 524288;
  int tw = t & 31, th = t >> 5;
#pragma unroll
  for (int i = 0; i < 8; ++i) {
    int c = i * 16 + th;
    xt[c][tw] = xb[c * 4096 + p0 + tw];
  }
  __syncthreads();
  int wid = t >> 6, lane = t & 63;
  float gg0 = g[lane], gg1 = g[lane + 64];
  float bb0 = be[lane], bb1 = be[lane + 64];
#pragma unroll
  for (int it = 0; it < 4; ++it) {
    int tt = wid * 4 + it;
    float v0 = xt[lane][tt], v1 = xt[lane + 64][tt];
    float s = v0 + v1, sq = v0 * v0 + v1 * v1;
#pragma unroll
    for (int off = 32; off; off >>= 1) {
      s += __shfl_xor(s, off);
      sq += __shfl_xor(sq, off);
    }
    float mu = s * (1.f / 128.f);
    float var = sq * (1.f / 128.f) - mu * mu;
    float rs = rsqrtf(var + 1e-5f);
    r[(size_t)(m0 + tt) * 128 + lane] = v0;
    r[(size_t)(m0 + tt) * 128 + 64 + lane] = v1;
    at[tt][lane] = __float2bfloat16((v0 - mu) * rs * gg0 + bb0);
    at[tt][lane + 64] = __float2bfloat16((v1 - mu) * rs * gg1 + bb1);
  }
  __syncthreads();
  int mw = wid >> 2, nwq = wid & 3;
  int lr = lane & 15, kg = lane >> 4;
  bf16x8 af[4];
#pragma unroll
  for (int ks = 0; ks < 4; ++ks)
    af[ks] = *reinterpret_cast<const bf16x8*>(&at[mw * 16 + lr][ks * 32 + kg * 8]);
  f32x4 acc[6];
#pragma unroll
  for (int nf = 0; nf < 6; ++nf) acc[nf] = f32x4{0, 0, 0, 0};
#pragma unroll
  for (int nf = 0; nf < 6; ++nf) {
    int o = nwq * 96 + nf * 16 + lr;
    const float* wp = qkv_w + o * 128 + kg * 8;
#pragma unroll
    for (int ks = 0; ks < 4; ++ks) {
      float4 wa = *reinterpret_cast<const float4*>(wp + ks * 32);
      float4 wc = *reinterpret_cast<const float4*>(wp + ks * 32 + 4);
      acc[nf] = __builtin_amdgcn_mfma_f32_16x16x32_bf16(af[ks], cvt8(wa, wc),
                                                        acc[nf], 0, 0, 0);
    }
  }
#pragma unroll
  for (int nf = 0; nf < 6; ++nf) {
    int o = nwq * 96 + nf * 16 + lr;
    float bv = qkv_b[o];
    float qs = (o < 128) ? QSCALE : 1.f;
#pragma unroll
    for (int rr = 0; rr < 4; ++rr) {
      int m = m0 + mw * 16 + kg * 4 + rr;
      qkvb[(size_t)m * 384 + o] = __float2bfloat16((acc[nf][rr] + bv) * qs);
    }
  }
}

// ---------------- K2: MFMA neighborhood attention, K-from-global, V staged packed ----------------
// R14: Vt staging rewritten as row-pair-packed b32 writes (lane = row-pair ->
// consecutive dwords, <=2-way banks) replacing the 16-way-conflicted b16
// scatter (inter-lane stride 1728B == 16 dwords mod 32 banks -> 4 bank groups).
// Same Vt layout/values; Pl after Vt in one smem[] (PV row-127 overflow lands
// in always-written P memory — R8/R9 lesson).
#define NB 98
#define VP 108
#define VPD 54
#define PP 132
__global__ __launch_bounds__(256) void k_attn4(
    const __hip_bfloat16* __restrict__ qkv, const float* __restrict__ rpb,
    __hip_bfloat16* __restrict__ ao) {
  __shared__ __align__(16) short smem[128 * VP + 4 * 8 * PP];
  short* Vt = smem;             // [128][VP]
  short* Pl = smem + 128 * VP;  // [4][8][PP]
  const short* qs = (const short*)qkv;
  int tid = threadIdx.x;
  // bijective XCD swizzle (1024 blocks % 8 == 0)
  int bid = blockIdx.x;
  int swz = (bid & 7) * 128 + (bid >> 3);
  int m0 = swz * 8;
  int b = m0 >> 12, hq = (m0 >> 6) & 63, c0 = m0 & 63;
  int hs = min(max(hq - 3, 0), 57);
  int cs0 = min(max(c0 - 3, 0), 50);
  unsigned* VtD = (unsigned*)Vt;
  // ---- stage V packed: lane = row-pair rp (0..48), g2 = d-quarter ----
  {
    int g2 = tid >> 6, rp = tid & 63;
    if (rp < 49) {
      int r0 = rp * 2, r1 = r0 + 1;
      int rh0 = r0 / 14, rc0 = r0 - rh0 * 14;
      int rh1 = r1 / 14, rc1 = r1 - rh1 * 14;
      int tr0 = b * 4096 + (hs + rh0) * 64 + min(cs0 + rc0, 63);
      int tr1 = b * 4096 + (hs + rh1) * 64 + min(cs0 + rc1, 63);
#pragma unroll
      for (int gg = 0; gg < 4; ++gg) {
        int d0 = (g2 * 4 + gg) * 8;
        const short* p0 = qs + (size_t)tr0 * 384 + 256 + d0;
        const short* p1 = qs + (size_t)tr1 * 384 + 256 + d0;
        short4 a0 = *(const short4*)p0, a1 = *(const short4*)(p0 + 4);
        short4 c0v = *(const short4*)p1, c1 = *(const short4*)(p1 + 4);
        unsigned bse = (unsigned)d0 * VPD + rp;
        VtD[bse + 0 * VPD] = (unsigned short)a0.x | ((unsigned)(unsigned short)c0v.x << 16);
        VtD[bse + 1 * VPD] = (unsigned short)a0.y | ((unsigned)(unsigned short)c0v.y << 16);
        VtD[bse + 2 * VPD] = (unsigned short)a0.z | ((unsigned)(unsigned short)c0v.z << 16);
        VtD[bse + 3 * VPD] = (unsigned short)a0.w | ((unsigned)(unsigned short)c0v.w << 16);
        VtD[bse + 4 * VPD] = (unsigned short)a1.x | ((unsigned)(unsigned short)c1.x << 16);
        VtD[bse + 5 * VPD] = (unsigned short)a1.y | ((unsigned)(unsigned short)c1.y << 16);
        VtD[bse + 6 * VPD] = (unsigned short)a1.z | ((unsigned)(unsigned short)c1.z << 16);
        VtD[bse + 7 * VPD] = (unsigned short)a1.w | ((unsigned)(unsigned short)c1.w << 16);
      }
    }
  }
  // zero Vt pad row-pairs 49..53 (rows 98..107)
  for (int i = tid; i < 128 * 5; i += 256) {
    int d = i / 5, j = i - d * 5;
    VtD[d * VPD + 49 + j] = 0;
  }
  int h = tid >> 6, lane = tid & 63;
  int lr = lane & 15, kg = lane >> 4;
  // ---- QK^T: 7 MFMAs, B-fragments straight from global (L2-hot) ----
  int qrow = min(m0 + lr, NTOK - 1);
  bf16x8 aq = *reinterpret_cast<const bf16x8*>(qs + (size_t)qrow * 384 + h * 32 + kg * 8);
  f32x4 sc[7];
#pragma unroll
  for (int nt = 0; nt < 7; ++nt) {
    int nbr = nt * 16 + lr;
    int rw = min(nbr, NB - 1);
    int rh = rw / 14, rc = rw - rh * 14;
    int tn = b * 4096 + (hs + rh) * 64 + min(cs0 + rc, 63);
    bf16x8 bk = *reinterpret_cast<const bf16x8*>(qs + (size_t)tn * 384 + 128 + h * 32 + kg * 8);
    sc[nt] = __builtin_amdgcn_mfma_f32_16x16x32_bf16(aq, bk, f32x4{0, 0, 0, 0}, 0, 0, 0);
  }
  // ---- rpb + mask + softmax (row = token on kg, col = neighbor on lr) ----
  int offv[4], cmt[4];
#pragma unroll
  for (int rr = 0; rr < 4; ++rr) {
    int ct = c0 + kg * 4 + rr;
    int ws0 = min(max(ct - 3, 0), 57);
    offv[rr] = ws0 - cs0;
    cmt[rr] = cs0 + 6 - ct;
  }
  float mx[4] = {-3e38f, -3e38f, -3e38f, -3e38f};
#pragma unroll
  for (int nt = 0; nt < 7; ++nt) {
    int nbr = nt * 16 + lr;
    int rh = nbr / 14, rc = nbr - rh * 14;
    bool vn = nbr < NB;
    int ribase = h * 169 + (hs - hq + 6 + rh) * 13 + rc;
#pragma unroll
    for (int rr = 0; rr < 4; ++rr) {
      float v = -1e30f;
      if (vn && (unsigned)(rc - offv[rr]) < 7u) v = sc[nt][rr] + rpb[ribase + cmt[rr]];
      sc[nt][rr] = v;
      mx[rr] = fmaxf(mx[rr], v);
    }
  }
#pragma unroll
  for (int rr = 0; rr < 4; ++rr) {
    mx[rr] = fmaxf(mx[rr], __shfl_xor(mx[rr], 1));
    mx[rr] = fmaxf(mx[rr], __shfl_xor(mx[rr], 2));
    mx[rr] = fmaxf(mx[rr], __shfl_xor(mx[rr], 4));
    mx[rr] = fmaxf(mx[rr], __shfl_xor(mx[rr], 8));
  }
  float sum[4] = {0.f, 0.f, 0.f, 0.f};
#pragma unroll
  for (int nt = 0; nt < 7; ++nt)
#pragma unroll
    for (int rr = 0; rr < 4; ++rr) {
      float e = __expf(sc[nt][rr] - mx[rr]);
      sc[nt][rr] = e;
      sum[rr] += e;
    }
#pragma unroll
  for (int rr = 0; rr < 4; ++rr) {
    sum[rr] += __shfl_xor(sum[rr], 1);
    sum[rr] += __shfl_xor(sum[rr], 2);
    sum[rr] += __shfl_xor(sum[rr], 4);
    sum[rr] += __shfl_xor(sum[rr], 8);
  }
  short* Ph = Pl + h * 8 * PP;
  if (kg < 2) {
#pragma unroll
    for (int rr = 0; rr < 4; ++rr) {
      float inv = 1.f / sum[rr];
      int tok = kg * 4 + rr;
#pragma unroll
      for (int nt = 0; nt < 7; ++nt)
        Ph[tok * PP + nt * 16 + lr] = f2bs(sc[nt][rr] * inv);
      Ph[tok * PP + 112 + lr] = 0;
      Ph[tok * PP + 128 + (lr & 3)] = 0;
    }
  }
  __syncthreads();  // Vt staged + P visible
  // ---- PV: 8 MFMAs ----
  f32x4 o[2] = {f32x4{0, 0, 0, 0}, f32x4{0, 0, 0, 0}};
#pragma unroll
  for (int kt = 0; kt < 4; ++kt) {
    bf16x8 ap = ld8(Ph + (lr & 7) * PP + kt * 32 + kg * 8);
#pragma unroll
    for (int dt = 0; dt < 2; ++dt) {
      bf16x8 bv = ld8(Vt + (h * 32 + dt * 16 + lr) * VP + kt * 32 + kg * 8);
      o[dt] = __builtin_amdgcn_mfma_f32_16x16x32_bf16(ap, bv, o[dt], 0, 0, 0);
    }
  }
  if (kg < 2) {
#pragma unroll
    for (int dt = 0; dt < 2; ++dt)
#pragma unroll
      for (int rr = 0; rr < 4; ++rr) {
        int tok = kg * 4 + rr;
        ao[(size_t)(m0 + tok) * 128 + h * 32 + dt * 16 + lr] =
            __float2bfloat16(o[dt][rr]);
      }
  }
}

// ---------------- K3: fused tail, 512 thr (8 waves = 2M x 4N, nf=2) ----------------
__global__ __launch_bounds__(512) void k_tail(
    const __hip_bfloat16* __restrict__ ao, const float* __restrict__ r,
    const __hip_bfloat16* __restrict__ wb, const float* __restrict__ bproj,
    const float* __restrict__ g2, const float* __restrict__ be2,
    const float* __restrict__ b1,
    const float* __restrict__ g3, const float* __restrict__ be3,
    const float* __restrict__ b2,
    const float* __restrict__ g4, const float* __restrict__ be4,
    const float* __restrict__ b3, float* __restrict__ out) {
  __shared__ __hip_bfloat16 abuf[32][136];
  __shared__ float2 red[2][4][16];
  int t = threadIdx.x, wid = t >> 6, lane = t & 63;
  int mw = wid >> 2, nwq = wid & 3;
  int lr = lane & 15, kg = lane >> 4;
  int m0 = blockIdx.x * 32;
  const __hip_bfloat16* wproj = wb;
  const __hip_bfloat16* w1 = wb + 16384;
  const __hip_bfloat16* w2 = wb + 32768;
  const __hip_bfloat16* w3 = wb + 49152;
  f32x4 acc[2];
  float x2f[2][4];

  auto gemm_glob = [&](const __hip_bfloat16* Aglob, const __hip_bfloat16* W) {
    bf16x8 af[4];
#pragma unroll
    for (int ks = 0; ks < 4; ++ks)
      af[ks] = *reinterpret_cast<const bf16x8*>(Aglob + (mw * 16 + lr) * 128 + ks * 32 + kg * 8);
#pragma unroll
    for (int nf = 0; nf < 2; ++nf) {
      int o = nwq * 32 + nf * 16 + lr;
      const __hip_bfloat16* wp = W + o * 128 + kg * 8;
      acc[nf] = f32x4{0, 0, 0, 0};
#pragma unroll
      for (int ks = 0; ks < 4; ++ks) {
        bf16x8 bfr = *reinterpret_cast<const bf16x8*>(wp + ks * 32);
        acc[nf] = __builtin_amdgcn_mfma_f32_16x16x32_bf16(af[ks], bfr, acc[nf], 0, 0, 0);
      }
    }
  };
  auto gemm_lds = [&](const __hip_bfloat16* W) {
    bf16x8 af[4];
#pragma unroll
    for (int ks = 0; ks < 4; ++ks)
      af[ks] = *reinterpret_cast<const bf16x8*>(&abuf[mw * 16 + lr][ks * 32 + kg * 8]);
#pragma unroll
    for (int nf = 0; nf < 2; ++nf) {
      int o = nwq * 32 + nf * 16 + lr;
      const __hip_bfloat16* wp = W + o * 128 + kg * 8;
      acc[nf] = f32x4{0, 0, 0, 0};
#pragma unroll
      for (int ks = 0; ks < 4; ++ks) {
        bf16x8 bfr = *reinterpret_cast<const bf16x8*>(wp + ks * 32);
        acc[nf] = __builtin_amdgcn_mfma_f32_16x16x32_bf16(af[ks], bfr, acc[nf], 0, 0, 0);
      }
    }
  };
  auto ln_store = [&](const float* g, const float* be) {
    float ps[4] = {0.f, 0.f, 0.f, 0.f}, pq[4] = {0.f, 0.f, 0.f, 0.f};
#pragma unroll
    for (int nf = 0; nf < 2; ++nf)
#pragma unroll
      for (int rr = 0; rr < 4; ++rr) {
        float v = acc[nf][rr];
        ps[rr] += v;
        pq[rr] += v * v;
      }
#pragma unroll
    for (int rr = 0; rr < 4; ++rr)
#pragma unroll
      for (int off = 1; off < 16; off <<= 1) {
        ps[rr] += __shfl_xor(ps[rr], off);
        pq[rr] += __shfl_xor(pq[rr], off);
      }
    if (lr == 0)
#pragma unroll
      for (int rr = 0; rr < 4; ++rr)
        red[mw][nwq][kg * 4 + rr] = make_float2(ps[rr], pq[rr]);
    __syncthreads();
    float mu[4], rs[4];
#pragma unroll
    for (int rr = 0; rr < 4; ++rr) {
      int r16 = kg * 4 + rr;
      float2 a0 = red[mw][0][r16], a1 = red[mw][1][r16];
      float2 a2 = red[mw][2][r16], a3 = red[mw][3][r16];
      float ssum = a0.x + a1.x + a2.x + a3.x;
      float qsum = a0.y + a1.y + a2.y + a3.y;
      mu[rr] = ssum * (1.f / 128.f);
      float var = qsum * (1.f / 128.f) - mu[rr] * mu[rr];
      rs[rr] = rsqrtf(var + 1e-5f);
    }
#pragma unroll
    for (int nf = 0; nf < 2; ++nf) {
      int o = nwq * 32 + nf * 16 + lr;
      float gv = g[o], bev = be[o];
#pragma unroll
      for (int rr = 0; rr < 4; ++rr)
        abuf[mw * 16 + kg * 4 + rr][o] =
            __float2bfloat16((acc[nf][rr] - mu[rr]) * rs[rr] * gv + bev);
    }
    __syncthreads();
  };

  // stage 1: proj + LN2
  gemm_glob(ao + (size_t)m0 * 128, wproj);
#pragma unroll
  for (int nf = 0; nf < 2; ++nf) {
    float bv = bproj[nwq * 32 + nf * 16 + lr];
#pragma unroll
    for (int rr = 0; rr < 4; ++rr) acc[nf][rr] += bv;
  }
  ln_store(g2, be2);

  // stage 2: w1 + residual r, save x2, LN3
  gemm_lds(w1);
  __syncthreads();
#pragma unroll
  for (int nf = 0; nf < 2; ++nf) {
    int o = nwq * 32 + nf * 16 + lr;
    float bv = b1[o];
#pragma unroll
    for (int rr = 0; rr < 4; ++rr) {
      int m = m0 + mw * 16 + kg * 4 + rr;
      float v = acc[nf][rr] + bv + r[(size_t)m * 128 + o];
      x2f[nf][rr] = v;
      acc[nf][rr] = v;
    }
  }
  ln_store(g3, be3);

  // stage 3: w2 + relu + LN4
  gemm_lds(w2);
  __syncthreads();
#pragma unroll
  for (int nf = 0; nf < 2; ++nf) {
    float bv = b2[nwq * 32 + nf * 16 + lr];
#pragma unroll
    for (int rr = 0; rr < 4; ++rr) acc[nf][rr] = fmaxf(acc[nf][rr] + bv, 0.f);
  }
  ln_store(g4, be4);

  // stage 4: w3 + x2 residual -> NCHW f32 out
  gemm_lds(w3);
#pragma unroll
  for (int nf = 0; nf < 2; ++nf) {
    int o = nwq * 32 + nf * 16 + lr;
    float bv = b3[o];
#pragma unroll
    for (int rr = 0; rr < 4; ++rr) {
      int m = m0 + mw * 16 + kg * 4 + rr;
      float v = acc[nf][rr] + bv + x2f[nf][rr];
      int bb = m >> 12, hw = m & 4095;
      out[(size_t)bb * 524288 + o * 4096 + hw] = v;
    }
  }
}

// ---------------- launch ----------------
extern "C" void kernel_launch(void* const* d_in, const int* in_sizes, int n_in,
                              void* d_out, int out_size, void* d_ws,
                              size_t ws_size, hipStream_t stream) {
  const float* x = (const float*)d_in[0];
  const float* g1 = (const float*)d_in[1];
  const float* be1 = (const float*)d_in[2];
  const float* g2 = (const float*)d_in[3];
  const float* be2 = (const float*)d_in[4];
  const float* g3 = (const float*)d_in[5];
  const float* be3 = (const float*)d_in[6];
  const float* g4 = (const float*)d_in[7];
  const float* be4 = (const float*)d_in[8];
  const float* qkv_w = (const float*)d_in[9];
  const float* qkv_b = (const float*)d_in[10];
  const float* rpb = (const float*)d_in[11];
  const float* proj_w = (const float*)d_in[12];
  const float* proj_b = (const float*)d_in[13];
  const float* w1 = (const float*)d_in[14];
  const float* bl1 = (const float*)d_in[15];
  const float* w2 = (const float*)d_in[16];
  const float* bl2 = (const float*)d_in[17];
  const float* w3 = (const float*)d_in[18];
  const float* bl3 = (const float*)d_in[19];

  char* ws = (char*)d_ws;
  __hip_bfloat16* wb = (__hip_bfloat16*)ws;               // [65536] tail weights bf16
  float* r = (float*)(ws + 262144);                       // [8192][128] f32
  __hip_bfloat16* qkvb = (__hip_bfloat16*)(ws + 4456448); // [8192][384] bf16
  __hip_bfloat16* ao = (__hip_bfloat16*)(ws + 10747904);  // [8192][128] bf16

  k_qkvcw<<<256, 512, 0, stream>>>(x, g1, be1, qkv_b, qkv_w, proj_w, w1, w2,
                                   w3, wb, r, qkvb);
  k_attn4<<<1024, 256, 0, stream>>>(qkvb, rpb, ao);
  k_tail<<<256, 512, 0, stream>>>(ao, r, wb, proj_b, g2, be2, bl1, g3, be3,
                                  bl2, g4, be4, bl3, (float*)d_out);
}

// Round 16
// 49.869 us; speedup vs baseline: 1.2709x; 1.0214x over previous
//
#include <hip/hip_runtime.h>
#include <hip/hip_bf16.h>
#include <cstdint>

typedef short bf16x8 __attribute__((ext_vector_type(8)));
typedef float f32x4 __attribute__((ext_vector_type(4)));

// Problem constants: B=2, DIM=128, H=64, W=64, DH=32, HEADS=4, K=7
#define NTOK 8192
#define QSCALE 0.17677669529663687f

__device__ inline float b2f(short s) {
  return __uint_as_float(((unsigned)(unsigned short)s) << 16);
}
__device__ inline short f2bs(float x) {
  __hip_bfloat16 b = __float2bfloat16(x);
  return *reinterpret_cast<short*>(&b);
}
__device__ inline bf16x8 ld8(const short* p) {
  short4 lo = *reinterpret_cast<const short4*>(p);
  short4 hi = *reinterpret_cast<const short4*>(p + 4);
  bf16x8 r;
  r[0] = lo.x; r[1] = lo.y; r[2] = lo.z; r[3] = lo.w;
  r[4] = hi.x; r[5] = hi.y; r[6] = hi.z; r[7] = hi.w;
  return r;
}
__device__ inline bf16x8 cvt8(float4 a, float4 c) {
  bf16x8 r;
  r[0] = f2bs(a.x); r[1] = f2bs(a.y); r[2] = f2bs(a.z); r[3] = f2bs(a.w);
  r[4] = f2bs(c.x); r[5] = f2bs(c.y); r[6] = f2bs(c.z); r[7] = f2bs(c.w);
  return r;
}

// ---------------- K1: weight convert + NCHW->NHWC + LN1 + QKV GEMM (512 thr) ----------------
__global__ __launch_bounds__(512) void k_qkvcw(
    const float* __restrict__ x, const float* __restrict__ g,
    const float* __restrict__ be, const float* __restrict__ qkv_b,
    const float* __restrict__ qkv_w, const float* __restrict__ pw,
    const float* __restrict__ w1f, const float* __restrict__ w2f,
    const float* __restrict__ w3f, __hip_bfloat16* __restrict__ wb,
    float* __restrict__ r, __hip_bfloat16* __restrict__ qkvb) {
  __shared__ float xt[128][33];
  __shared__ __hip_bfloat16 at[32][136];
  int t = threadIdx.x;
  if (t < 256) {
    int ci = blockIdx.x * 256 + t;
    float cv;
    if (ci < 16384) cv = pw[ci];
    else if (ci < 32768) cv = w1f[ci - 16384];
    else if (ci < 49152) cv = w2f[ci - 32768];
    else cv = w3f[ci - 49152];
    wb[ci] = __float2bfloat16(cv);
  }
  int m0 = blockIdx.x * 32;
  int b = m0 >> 12;
  int p0 = m0 & 4095;
  const float* xb = x + (size_t)b * 524288;
  int tw = t & 31, th = t >> 5;
#pragma unroll
  for (int i = 0; i < 8; ++i) {
    int c = i * 16 + th;
    xt[c][tw] = xb[c * 4096 + p0 + tw];
  }
  __syncthreads();
  int wid = t >> 6, lane = t & 63;
  float gg0 = g[lane], gg1 = g[lane + 64];
  float bb0 = be[lane], bb1 = be[lane + 64];
#pragma unroll
  for (int it = 0; it < 4; ++it) {
    int tt = wid * 4 + it;
    float v0 = xt[lane][tt], v1 = xt[lane + 64][tt];
    float s = v0 + v1, sq = v0 * v0 + v1 * v1;
#pragma unroll
    for (int off = 32; off; off >>= 1) {
      s += __shfl_xor(s, off);
      sq += __shfl_xor(sq, off);
    }
    float mu = s * (1.f / 128.f);
    float var = sq * (1.f / 128.f) - mu * mu;
    float rs = rsqrtf(var + 1e-5f);
    r[(size_t)(m0 + tt) * 128 + lane] = v0;
    r[(size_t)(m0 + tt) * 128 + 64 + lane] = v1;
    at[tt][lane] = __float2bfloat16((v0 - mu) * rs * gg0 + bb0);
    at[tt][lane + 64] = __float2bfloat16((v1 - mu) * rs * gg1 + bb1);
  }
  __syncthreads();
  int mw = wid >> 2, nwq = wid & 3;
  int lr = lane & 15, kg = lane >> 4;
  bf16x8 af[4];
#pragma unroll
  for (int ks = 0; ks < 4; ++ks)
    af[ks] = *reinterpret_cast<const bf16x8*>(&at[mw * 16 + lr][ks * 32 + kg * 8]);
  f32x4 acc[6];
#pragma unroll
  for (int nf = 0; nf < 6; ++nf) acc[nf] = f32x4{0, 0, 0, 0};
#pragma unroll
  for (int nf = 0; nf < 6; ++nf) {
    int o = nwq * 96 + nf * 16 + lr;
    const float* wp = qkv_w + o * 128 + kg * 8;
#pragma unroll
    for (int ks = 0; ks < 4; ++ks) {
      float4 wa = *reinterpret_cast<const float4*>(wp + ks * 32);
      float4 wc = *reinterpret_cast<const float4*>(wp + ks * 32 + 4);
      acc[nf] = __builtin_amdgcn_mfma_f32_16x16x32_bf16(af[ks], cvt8(wa, wc),
                                                        acc[nf], 0, 0, 0);
    }
  }
#pragma unroll
  for (int nf = 0; nf < 6; ++nf) {
    int o = nwq * 96 + nf * 16 + lr;
    float bv = qkv_b[o];
    float qs = (o < 128) ? QSCALE : 1.f;
#pragma unroll
    for (int rr = 0; rr < 4; ++rr) {
      int m = m0 + mw * 16 + kg * 4 + rr;
      qkvb[(size_t)m * 384 + o] = __float2bfloat16((acc[nf][rr] + bv) * qs);
    }
  }
}

// ---------------- K2: fused attn (2 strips, wave=(strip,head)) + tail, 16 tok/block ----------------
// Grid 512 x 512thr, LDS 77.6KB -> 2 blocks/CU = 16 waves/CU (attn occupancy
// preserved vs standalone; tail doubled). smem carve order [Vt0|Vt1|Pl] keeps
// the PV row-127 k=108..127 over-read inside always-written LDS (R8/R9 lesson):
// strip0 -> Vt1, strip1 -> Pl[0..18].
#define NB 98
#define VP 108
#define VPD 54
#define PP 132
#define VTSH 13824  // shorts per Vt buffer (128*VP)
__global__ __launch_bounds__(512, 4) void k_fuse3(
    const __hip_bfloat16* __restrict__ qkvb, const float* __restrict__ rpb,
    const float* __restrict__ r, const __hip_bfloat16* __restrict__ wb,
    const float* __restrict__ bproj,
    const float* __restrict__ g2, const float* __restrict__ be2,
    const float* __restrict__ b1,
    const float* __restrict__ g3, const float* __restrict__ be3,
    const float* __restrict__ b2,
    const float* __restrict__ g4, const float* __restrict__ be4,
    const float* __restrict__ b3, float* __restrict__ out) {
  __shared__ __align__(16) short smem[2 * VTSH + 2 * 4 * 8 * PP];
  __shared__ __align__(16) __hip_bfloat16 abuf[16][136];
  __shared__ float2 red[8][16];
  const short* qs = (const short*)qkvb;
  int tid = threadIdx.x;
  int bid = blockIdx.x;
  int swz = (bid & 7) * 64 + (bid >> 3);  // bijective XCD swizzle (512%8==0)
  int m0 = swz * 16;
  int b = m0 >> 12, hq = (m0 >> 6) & 63;
  int hs = min(max(hq - 3, 0), 57);
  const __hip_bfloat16* wproj = wb;
  const __hip_bfloat16* w1 = wb + 16384;
  const __hip_bfloat16* w2 = wb + 32768;
  const __hip_bfloat16* w3 = wb + 49152;

  // ---- stage V for both strips (half-block each), packed b32 (R15-proven) ----
  {
    int half = tid >> 8;  // strip staged by this half-block
    int tl = tid & 255;
    int c0h = (m0 & 63) + half * 8;
    int csh = min(max(c0h - 3, 0), 50);
    unsigned* VtD = (unsigned*)(smem + half * VTSH);
    int g2i = tl >> 6, rp = tl & 63;
    if (rp < 49) {
      int r0 = rp * 2, r1 = r0 + 1;
      int rh0 = r0 / 14, rc0 = r0 - rh0 * 14;
      int rh1 = r1 / 14, rc1 = r1 - rh1 * 14;
      int tr0 = b * 4096 + (hs + rh0) * 64 + min(csh + rc0, 63);
      int tr1 = b * 4096 + (hs + rh1) * 64 + min(csh + rc1, 63);
#pragma unroll
      for (int gg = 0; gg < 4; ++gg) {
        int d0 = (g2i * 4 + gg) * 8;
        const short* p0 = qs + (size_t)tr0 * 384 + 256 + d0;
        const short* p1 = qs + (size_t)tr1 * 384 + 256 + d0;
        short4 a0 = *(const short4*)p0, a1 = *(const short4*)(p0 + 4);
        short4 c0v = *(const short4*)p1, c1 = *(const short4*)(p1 + 4);
        unsigned bse = (unsigned)d0 * VPD + rp;
        VtD[bse + 0 * VPD] = (unsigned short)a0.x | ((unsigned)(unsigned short)c0v.x << 16);
        VtD[bse + 1 * VPD] = (unsigned short)a0.y | ((unsigned)(unsigned short)c0v.y << 16);
        VtD[bse + 2 * VPD] = (unsigned short)a0.z | ((unsigned)(unsigned short)c0v.z << 16);
        VtD[bse + 3 * VPD] = (unsigned short)a0.w | ((unsigned)(unsigned short)c0v.w << 16);
        VtD[bse + 4 * VPD] = (unsigned short)a1.x | ((unsigned)(unsigned short)c1.x << 16);
        VtD[bse + 5 * VPD] = (unsigned short)a1.y | ((unsigned)(unsigned short)c1.y << 16);
        VtD[bse + 6 * VPD] = (unsigned short)a1.z | ((unsigned)(unsigned short)c1.z << 16);
        VtD[bse + 7 * VPD] = (unsigned short)a1.w | ((unsigned)(unsigned short)c1.w << 16);
      }
    }
    for (int i = tl; i < 128 * 5; i += 256) {  // zero pad rows 98..107
      int d = i / 5, j = i - d * 5;
      VtD[d * VPD + 49 + j] = 0;
    }
  }

  // ---- attention: wave = (strip, head) ----
  int wid = tid >> 6, lane = tid & 63;
  int sst = wid >> 2, h = wid & 3;
  int lr = lane & 15, kg = lane >> 4;
  int m0s = m0 + sst * 8;
  int c0s = (m0 & 63) + sst * 8;
  int cs0 = min(max(c0s - 3, 0), 50);
  // QK^T: 7 MFMAs, B-fragments straight from global (L2-hot)
  int qrow = min(m0s + lr, NTOK - 1);
  bf16x8 aq = *reinterpret_cast<const bf16x8*>(qs + (size_t)qrow * 384 + h * 32 + kg * 8);
  f32x4 sc[7];
#pragma unroll
  for (int nt = 0; nt < 7; ++nt) {
    int nbr = nt * 16 + lr;
    int rw = min(nbr, NB - 1);
    int rh = rw / 14, rc = rw - rh * 14;
    int tn = b * 4096 + (hs + rh) * 64 + min(cs0 + rc, 63);
    bf16x8 bk = *reinterpret_cast<const bf16x8*>(qs + (size_t)tn * 384 + 128 + h * 32 + kg * 8);
    sc[nt] = __builtin_amdgcn_mfma_f32_16x16x32_bf16(aq, bk, f32x4{0, 0, 0, 0}, 0, 0, 0);
  }
  // rpb + mask + softmax (row = token on kg, col = neighbor on lr)
  int offv[4], cmt[4];
#pragma unroll
  for (int rr = 0; rr < 4; ++rr) {
    int ct = c0s + kg * 4 + rr;
    int ws0 = min(max(ct - 3, 0), 57);
    offv[rr] = ws0 - cs0;
    cmt[rr] = cs0 + 6 - ct;
  }
  float mx[4] = {-3e38f, -3e38f, -3e38f, -3e38f};
#pragma unroll
  for (int nt = 0; nt < 7; ++nt) {
    int nbr = nt * 16 + lr;
    int rh = nbr / 14, rc = nbr - rh * 14;
    bool vn = nbr < NB;
    int ribase = h * 169 + (hs - hq + 6 + rh) * 13 + rc;
#pragma unroll
    for (int rr = 0; rr < 4; ++rr) {
      float v = -1e30f;
      if (vn && (unsigned)(rc - offv[rr]) < 7u) v = sc[nt][rr] + rpb[ribase + cmt[rr]];
      sc[nt][rr] = v;
      mx[rr] = fmaxf(mx[rr], v);
    }
  }
#pragma unroll
  for (int rr = 0; rr < 4; ++rr) {
    mx[rr] = fmaxf(mx[rr], __shfl_xor(mx[rr], 1));
    mx[rr] = fmaxf(mx[rr], __shfl_xor(mx[rr], 2));
    mx[rr] = fmaxf(mx[rr], __shfl_xor(mx[rr], 4));
    mx[rr] = fmaxf(mx[rr], __shfl_xor(mx[rr], 8));
  }
  float sum[4] = {0.f, 0.f, 0.f, 0.f};
#pragma unroll
  for (int nt = 0; nt < 7; ++nt)
#pragma unroll
    for (int rr = 0; rr < 4; ++rr) {
      float e = __expf(sc[nt][rr] - mx[rr]);
      sc[nt][rr] = e;
      sum[rr] += e;
    }
#pragma unroll
  for (int rr = 0; rr < 4; ++rr) {
    sum[rr] += __shfl_xor(sum[rr], 1);
    sum[rr] += __shfl_xor(sum[rr], 2);
    sum[rr] += __shfl_xor(sum[rr], 4);
    sum[rr] += __shfl_xor(sum[rr], 8);
  }
  short* Ph = smem + 2 * VTSH + ((sst * 4 + h) * 8) * PP;
  if (kg < 2) {
#pragma unroll
    for (int rr = 0; rr < 4; ++rr) {
      float inv = 1.f / sum[rr];
      int tok = kg * 4 + rr;
#pragma unroll
      for (int nt = 0; nt < 7; ++nt)
        Ph[tok * PP + nt * 16 + lr] = f2bs(sc[nt][rr] * inv);
      Ph[tok * PP + 112 + lr] = 0;
      Ph[tok * PP + 128 + (lr & 3)] = 0;
    }
  }
  __syncthreads();  // Vt (both strips) staged + P visible
  // PV: 8 MFMAs -> abuf
  {
    const short* Vts = smem + sst * VTSH;
    f32x4 o2[2] = {f32x4{0, 0, 0, 0}, f32x4{0, 0, 0, 0}};
#pragma unroll
    for (int kt = 0; kt < 4; ++kt) {
      bf16x8 ap = ld8(Ph + (lr & 7) * PP + kt * 32 + kg * 8);
#pragma unroll
      for (int dt = 0; dt < 2; ++dt) {
        bf16x8 bv = ld8(Vts + (h * 32 + dt * 16 + lr) * VP + kt * 32 + kg * 8);
        o2[dt] = __builtin_amdgcn_mfma_f32_16x16x32_bf16(ap, bv, o2[dt], 0, 0, 0);
      }
    }
    if (kg < 2) {
#pragma unroll
      for (int dt = 0; dt < 2; ++dt)
#pragma unroll
        for (int rr = 0; rr < 4; ++rr)
          abuf[sst * 8 + kg * 4 + rr][h * 32 + dt * 16 + lr] =
              __float2bfloat16(o2[dt][rr]);
    }
  }
  __syncthreads();  // abuf complete

  // ---- tail: proj+LN2 -> w1+res+LN3 -> w2+relu+LN4 -> w3+res -> NCHW ----
  // M=16 (token = lr / kg*4+rr), wave = 16-col group (o = wid*16+lr), nf=1
  f32x4 acc;
  float x2f[4];

  auto gemm_lds = [&](const __hip_bfloat16* W) {
    bf16x8 af[4];
#pragma unroll
    for (int ks = 0; ks < 4; ++ks)
      af[ks] = *reinterpret_cast<const bf16x8*>(&abuf[lr][ks * 32 + kg * 8]);
    int o = wid * 16 + lr;
    const __hip_bfloat16* wp = W + o * 128 + kg * 8;
    acc = f32x4{0, 0, 0, 0};
#pragma unroll
    for (int ks = 0; ks < 4; ++ks) {
      bf16x8 bfr = *reinterpret_cast<const bf16x8*>(wp + ks * 32);
      acc = __builtin_amdgcn_mfma_f32_16x16x32_bf16(af[ks], bfr, acc, 0, 0, 0);
    }
  };
  auto ln_store = [&](const float* g, const float* be) {
    float ps[4], pq[4];
#pragma unroll
    for (int rr = 0; rr < 4; ++rr) {
      ps[rr] = acc[rr];
      pq[rr] = acc[rr] * acc[rr];
    }
#pragma unroll
    for (int rr = 0; rr < 4; ++rr)
#pragma unroll
      for (int off = 1; off < 16; off <<= 1) {
        ps[rr] += __shfl_xor(ps[rr], off);
        pq[rr] += __shfl_xor(pq[rr], off);
      }
    if (lr == 0)
#pragma unroll
      for (int rr = 0; rr < 4; ++rr)
        red[wid][kg * 4 + rr] = make_float2(ps[rr], pq[rr]);
    __syncthreads();  // red ready; also orders abuf reads before rewrites
    float mu[4], rs[4];
#pragma unroll
    for (int rr = 0; rr < 4; ++rr) {
      int r16 = kg * 4 + rr;
      float ssum = 0.f, qsum = 0.f;
#pragma unroll
      for (int w = 0; w < 8; ++w) {
        float2 a = red[w][r16];
        ssum += a.x;
        qsum += a.y;
      }
      mu[rr] = ssum * (1.f / 128.f);
      float var = qsum * (1.f / 128.f) - mu[rr] * mu[rr];
      rs[rr] = rsqrtf(var + 1e-5f);
    }
    int o = wid * 16 + lr;
    float gv = g[o], bev = be[o];
#pragma unroll
    for (int rr = 0; rr < 4; ++rr)
      abuf[kg * 4 + rr][o] =
          __float2bfloat16((acc[rr] - mu[rr]) * rs[rr] * gv + bev);
    __syncthreads();
  };

  // stage 1: proj + LN2 (A = attn output already in abuf)
  gemm_lds(wproj);
  {
    float bv = bproj[wid * 16 + lr];
#pragma unroll
    for (int rr = 0; rr < 4; ++rr) acc[rr] += bv;
  }
  ln_store(g2, be2);

  // stage 2: w1 + residual r, save x2, LN3
  gemm_lds(w1);
  {
    int o = wid * 16 + lr;
    float bv = b1[o];
#pragma unroll
    for (int rr = 0; rr < 4; ++rr) {
      int m = m0 + kg * 4 + rr;
      float v = acc[rr] + bv + r[(size_t)m * 128 + o];
      x2f[rr] = v;
      acc[rr] = v;
    }
  }
  ln_store(g3, be3);

  // stage 3: w2 + relu + LN4
  gemm_lds(w2);
  {
    float bv = b2[wid * 16 + lr];
#pragma unroll
    for (int rr = 0; rr < 4; ++rr) acc[rr] = fmaxf(acc[rr] + bv, 0.f);
  }
  ln_store(g4, be4);

  // stage 4: w3 + x2 residual -> NCHW f32 out
  gemm_lds(w3);
  {
    int o = wid * 16 + lr;
    float bv = b3[o];
#pragma unroll
    for (int rr = 0; rr < 4; ++rr) {
      int m = m0 + kg * 4 + rr;
      float v = acc[rr] + bv + x2f[rr];
      int bb = m >> 12, hw = m & 4095;
      out[(size_t)bb * 524288 + o * 4096 + hw] = v;
    }
  }
}

// ---------------- launch ----------------
extern "C" void kernel_launch(void* const* d_in, const int* in_sizes, int n_in,
                              void* d_out, int out_size, void* d_ws,
                              size_t ws_size, hipStream_t stream) {
  const float* x = (const float*)d_in[0];
  const float* g1 = (const float*)d_in[1];
  const float* be1 = (const float*)d_in[2];
  const float* g2 = (const float*)d_in[3];
  const float* be2 = (const float*)d_in[4];
  const float* g3 = (const float*)d_in[5];
  const float* be3 = (const float*)d_in[6];
  const float* g4 = (const float*)d_in[7];
  const float* be4 = (const float*)d_in[8];
  const float* qkv_w = (const float*)d_in[9];
  const float* qkv_b = (const float*)d_in[10];
  const float* rpb = (const float*)d_in[11];
  const float* proj_w = (const float*)d_in[12];
  const float* proj_b = (const float*)d_in[13];
  const float* w1 = (const float*)d_in[14];
  const float* bl1 = (const float*)d_in[15];
  const float* w2 = (const float*)d_in[16];
  const float* bl2 = (const float*)d_in[17];
  const float* w3 = (const float*)d_in[18];
  const float* bl3 = (const float*)d_in[19];

  char* ws = (char*)d_ws;
  __hip_bfloat16* wb = (__hip_bfloat16*)ws;               // [65536] tail weights bf16
  float* r = (float*)(ws + 262144);                       // [8192][128] f32
  __hip_bfloat16* qkvb = (__hip_bfloat16*)(ws + 4456448); // [8192][384] bf16

  k_qkvcw<<<256, 512, 0, stream>>>(x, g1, be1, qkv_b, qkv_w, proj_w, w1, w2,
                                   w3, wb, r, qkvb);
  k_fuse3<<<512, 512, 0, stream>>>(qkvb, rpb, r, wb, proj_b, g2, be2, bl1, g3,
                                   be3, bl2, g4, be4, bl3, (float*)d_out);
}

// Round 18
// 49.767 us; speedup vs baseline: 1.2735x; 1.0020x over previous
//
#include <hip/hip_runtime.h>
#include <hip/hip_bf16.h>
#include <cstdint>

typedef short bf16x8 __attribute__((ext_vector_type(8)));
typedef float f32x4 __attribute__((ext_vector_type(4)));

// Problem constants: B=2, DIM=128, H=64, W=64, DH=32, HEADS=4, K=7
#define NTOK 8192
#define QSCALE 0.17677669529663687f

__device__ inline float b2f(short s) {
  return __uint_as_float(((unsigned)(unsigned short)s) << 16);
}
__device__ inline short f2bs(float x) {
  __hip_bfloat16 b = __float2bfloat16(x);
  return *reinterpret_cast<short*>(&b);
}
__device__ inline bf16x8 ld8(const short* p) {
  short4 lo = *reinterpret_cast<const short4*>(p);
  short4 hi = *reinterpret_cast<const short4*>(p + 4);
  bf16x8 r;
  r[0] = lo.x; r[1] = lo.y; r[2] = lo.z; r[3] = lo.w;
  r[4] = hi.x; r[5] = hi.y; r[6] = hi.z; r[7] = hi.w;
  return r;
}
__device__ inline bf16x8 cvt8(float4 a, float4 c) {
  bf16x8 r;
  r[0] = f2bs(a.x); r[1] = f2bs(a.y); r[2] = f2bs(a.z); r[3] = f2bs(a.w);
  r[4] = f2bs(c.x); r[5] = f2bs(c.y); r[6] = f2bs(c.z); r[7] = f2bs(c.w);
  return r;
}

// ---------------- K1: weight convert + NCHW->NHWC + LN1 + QKV GEMM ----------------
// R17: 512 blocks x 16 tokens (was 256 x 32) -> LDS 13KB, 2 blocks/CU for
// latency hiding. GEMM M=16, 8 waves = 8 col-groups of 48 (nf=3).
__global__ __launch_bounds__(512) void k_qkvcw(
    const float* __restrict__ x, const float* __restrict__ g,
    const float* __restrict__ be, const float* __restrict__ qkv_b,
    const float* __restrict__ qkv_w, const float* __restrict__ pw,
    const float* __restrict__ w1f, const float* __restrict__ w2f,
    const float* __restrict__ w3f, __hip_bfloat16* __restrict__ wb,
    float* __restrict__ r, __hip_bfloat16* __restrict__ qkvb) {
  __shared__ float xt[128][17];
  __shared__ __hip_bfloat16 at[16][136];
  int t = threadIdx.x;
  // --- prologue: convert tail weights (65536 elems over 512 blocks x 128 lanes) ---
  if (t < 128) {
    int ci = blockIdx.x * 128 + t;
    float cv;
    if (ci < 16384) cv = pw[ci];
    else if (ci < 32768) cv = w1f[ci - 16384];
    else if (ci < 49152) cv = w2f[ci - 32768];
    else cv = w3f[ci - 49152];
    wb[ci] = __float2bfloat16(cv);
  }
  int m0 = blockIdx.x * 16;
  int b = m0 >> 12;
  int p0 = m0 & 4095;
  const float* xb = x + (size_t)b * 524288;
  int tw = t & 15, th = t >> 4;  // th 0..31
#pragma unroll
  for (int i = 0; i < 4; ++i) {
    int c = i * 32 + th;
    xt[c][tw] = xb[c * 4096 + p0 + tw];
  }
  __syncthreads();
  int wid = t >> 6, lane = t & 63;  // wid 0..7
  float gg0 = g[lane], gg1 = g[lane + 64];
  float bb0 = be[lane], bb1 = be[lane + 64];
#pragma unroll
  for (int it = 0; it < 2; ++it) {
    int tt = wid * 2 + it;
    float v0 = xt[lane][tt], v1 = xt[lane + 64][tt];
    float s = v0 + v1, sq = v0 * v0 + v1 * v1;
#pragma unroll
    for (int off = 32; off; off >>= 1) {
      s += __shfl_xor(s, off);
      sq += __shfl_xor(sq, off);
    }
    float mu = s * (1.f / 128.f);
    float var = sq * (1.f / 128.f) - mu * mu;
    float rs = rsqrtf(var + 1e-5f);
    r[(size_t)(m0 + tt) * 128 + lane] = v0;
    r[(size_t)(m0 + tt) * 128 + 64 + lane] = v1;
    at[tt][lane] = __float2bfloat16((v0 - mu) * rs * gg0 + bb0);
    at[tt][lane + 64] = __float2bfloat16((v1 - mu) * rs * gg1 + bb1);
  }
  __syncthreads();
  // GEMM 16x384: 8 waves = 8 col-groups of 48 (nf=3)
  int lr = lane & 15, kg = lane >> 4;
  bf16x8 af[4];
#pragma unroll
  for (int ks = 0; ks < 4; ++ks)
    af[ks] = *reinterpret_cast<const bf16x8*>(&at[lr][ks * 32 + kg * 8]);
  f32x4 acc[3];
#pragma unroll
  for (int nf = 0; nf < 3; ++nf) acc[nf] = f32x4{0, 0, 0, 0};
#pragma unroll
  for (int nf = 0; nf < 3; ++nf) {
    int o = wid * 48 + nf * 16 + lr;
    const float* wp = qkv_w + o * 128 + kg * 8;
#pragma unroll
    for (int ks = 0; ks < 4; ++ks) {
      float4 wa = *reinterpret_cast<const float4*>(wp + ks * 32);
      float4 wc = *reinterpret_cast<const float4*>(wp + ks * 32 + 4);
      acc[nf] = __builtin_amdgcn_mfma_f32_16x16x32_bf16(af[ks], cvt8(wa, wc),
                                                        acc[nf], 0, 0, 0);
    }
  }
#pragma unroll
  for (int nf = 0; nf < 3; ++nf) {
    int o = wid * 48 + nf * 16 + lr;
    float bv = qkv_b[o];
    float qs = (o < 128) ? QSCALE : 1.f;
#pragma unroll
    for (int rr = 0; rr < 4; ++rr) {
      int m = m0 + kg * 4 + rr;
      qkvb[(size_t)m * 384 + o] = __float2bfloat16((acc[nf][rr] + bv) * qs);
    }
  }
}

// ---------------- K2: fused attn (2 strips, wave=(strip,head)) + tail, 16 tok/block ----------------
// (unchanged from R16 — proven at 49.9us)
#define NB 98
#define VP 108
#define VPD 54
#define PP 132
#define VTSH 13824  // shorts per Vt buffer (128*VP)
__global__ __launch_bounds__(512, 4) void k_fuse3(
    const __hip_bfloat16* __restrict__ qkvb, const float* __restrict__ rpb,
    const float* __restrict__ r, const __hip_bfloat16* __restrict__ wb,
    const float* __restrict__ bproj,
    const float* __restrict__ g2, const float* __restrict__ be2,
    const float* __restrict__ b1,
    const float* __restrict__ g3, const float* __restrict__ be3,
    const float* __restrict__ b2,
    const float* __restrict__ g4, const float* __restrict__ be4,
    const float* __restrict__ b3, float* __restrict__ out) {
  __shared__ __align__(16) short smem[2 * VTSH + 2 * 4 * 8 * PP];
  __shared__ __align__(16) __hip_bfloat16 abuf[16][136];
  __shared__ float2 red[8][16];
  const short* qs = (const short*)qkvb;
  int tid = threadIdx.x;
  int bid = blockIdx.x;
  int swz = (bid & 7) * 64 + (bid >> 3);  // bijective XCD swizzle (512%8==0)
  int m0 = swz * 16;
  int b = m0 >> 12, hq = (m0 >> 6) & 63;
  int hs = min(max(hq - 3, 0), 57);
  const __hip_bfloat16* wproj = wb;
  const __hip_bfloat16* w1 = wb + 16384;
  const __hip_bfloat16* w2 = wb + 32768;
  const __hip_bfloat16* w3 = wb + 49152;

  // ---- stage V for both strips (half-block each), packed b32 ----
  {
    int half = tid >> 8;
    int tl = tid & 255;
    int c0h = (m0 & 63) + half * 8;
    int csh = min(max(c0h - 3, 0), 50);
    unsigned* VtD = (unsigned*)(smem + half * VTSH);
    int g2i = tl >> 6, rp = tl & 63;
    if (rp < 49) {
      int r0 = rp * 2, r1 = r0 + 1;
      int rh0 = r0 / 14, rc0 = r0 - rh0 * 14;
      int rh1 = r1 / 14, rc1 = r1 - rh1 * 14;
      int tr0 = b * 4096 + (hs + rh0) * 64 + min(csh + rc0, 63);
      int tr1 = b * 4096 + (hs + rh1) * 64 + min(csh + rc1, 63);
#pragma unroll
      for (int gg = 0; gg < 4; ++gg) {
        int d0 = (g2i * 4 + gg) * 8;
        const short* p0 = qs + (size_t)tr0 * 384 + 256 + d0;
        const short* p1 = qs + (size_t)tr1 * 384 + 256 + d0;
        short4 a0 = *(const short4*)p0, a1 = *(const short4*)(p0 + 4);
        short4 c0v = *(const short4*)p1, c1 = *(const short4*)(p1 + 4);
        unsigned bse = (unsigned)d0 * VPD + rp;
        VtD[bse + 0 * VPD] = (unsigned short)a0.x | ((unsigned)(unsigned short)c0v.x << 16);
        VtD[bse + 1 * VPD] = (unsigned short)a0.y | ((unsigned)(unsigned short)c0v.y << 16);
        VtD[bse + 2 * VPD] = (unsigned short)a0.z | ((unsigned)(unsigned short)c0v.z << 16);
        VtD[bse + 3 * VPD] = (unsigned short)a0.w | ((unsigned)(unsigned short)c0v.w << 16);
        VtD[bse + 4 * VPD] = (unsigned short)a1.x | ((unsigned)(unsigned short)c1.x << 16);
        VtD[bse + 5 * VPD] = (unsigned short)a1.y | ((unsigned)(unsigned short)c1.y << 16);
        VtD[bse + 6 * VPD] = (unsigned short)a1.z | ((unsigned)(unsigned short)c1.z << 16);
        VtD[bse + 7 * VPD] = (unsigned short)a1.w | ((unsigned)(unsigned short)c1.w << 16);
      }
    }
    for (int i = tl; i < 128 * 5; i += 256) {
      int d = i / 5, j = i - d * 5;
      VtD[d * VPD + 49 + j] = 0;
    }
  }

  // ---- attention: wave = (strip, head) ----
  int wid = tid >> 6, lane = tid & 63;
  int sst = wid >> 2, h = wid & 3;
  int lr = lane & 15, kg = lane >> 4;
  int m0s = m0 + sst * 8;
  int c0s = (m0 & 63) + sst * 8;
  int cs0 = min(max(c0s - 3, 0), 50);
  int qrow = min(m0s + lr, NTOK - 1);
  bf16x8 aq = *reinterpret_cast<const bf16x8*>(qs + (size_t)qrow * 384 + h * 32 + kg * 8);
  f32x4 sc[7];
#pragma unroll
  for (int nt = 0; nt < 7; ++nt) {
    int nbr = nt * 16 + lr;
    int rw = min(nbr, NB - 1);
    int rh = rw / 14, rc = rw - rh * 14;
    int tn = b * 4096 + (hs + rh) * 64 + min(cs0 + rc, 63);
    bf16x8 bk = *reinterpret_cast<const bf16x8*>(qs + (size_t)tn * 384 + 128 + h * 32 + kg * 8);
    sc[nt] = __builtin_amdgcn_mfma_f32_16x16x32_bf16(aq, bk, f32x4{0, 0, 0, 0}, 0, 0, 0);
  }
  int offv[4], cmt[4];
#pragma unroll
  for (int rr = 0; rr < 4; ++rr) {
    int ct = c0s + kg * 4 + rr;
    int ws0 = min(max(ct - 3, 0), 57);
    offv[rr] = ws0 - cs0;
    cmt[rr] = cs0 + 6 - ct;
  }
  float mx[4] = {-3e38f, -3e38f, -3e38f, -3e38f};
#pragma unroll
  for (int nt = 0; nt < 7; ++nt) {
    int nbr = nt * 16 + lr;
    int rh = nbr / 14, rc = nbr - rh * 14;
    bool vn = nbr < NB;
    int ribase = h * 169 + (hs - hq + 6 + rh) * 13 + rc;
#pragma unroll
    for (int rr = 0; rr < 4; ++rr) {
      float v = -1e30f;
      if (vn && (unsigned)(rc - offv[rr]) < 7u) v = sc[nt][rr] + rpb[ribase + cmt[rr]];
      sc[nt][rr] = v;
      mx[rr] = fmaxf(mx[rr], v);
    }
  }
#pragma unroll
  for (int rr = 0; rr < 4; ++rr) {
    mx[rr] = fmaxf(mx[rr], __shfl_xor(mx[rr], 1));
    mx[rr] = fmaxf(mx[rr], __shfl_xor(mx[rr], 2));
    mx[rr] = fmaxf(mx[rr], __shfl_xor(mx[rr], 4));
    mx[rr] = fmaxf(mx[rr], __shfl_xor(mx[rr], 8));
  }
  float sum[4] = {0.f, 0.f, 0.f, 0.f};
#pragma unroll
  for (int nt = 0; nt < 7; ++nt)
#pragma unroll
    for (int rr = 0; rr < 4; ++rr) {
      float e = __expf(sc[nt][rr] - mx[rr]);
      sc[nt][rr] = e;
      sum[rr] += e;
    }
#pragma unroll
  for (int rr = 0; rr < 4; ++rr) {
    sum[rr] += __shfl_xor(sum[rr], 1);
    sum[rr] += __shfl_xor(sum[rr], 2);
    sum[rr] += __shfl_xor(sum[rr], 4);
    sum[rr] += __shfl_xor(sum[rr], 8);
  }
  short* Ph = smem + 2 * VTSH + ((sst * 4 + h) * 8) * PP;
  if (kg < 2) {
#pragma unroll
    for (int rr = 0; rr < 4; ++rr) {
      float inv = 1.f / sum[rr];
      int tok = kg * 4 + rr;
#pragma unroll
      for (int nt = 0; nt < 7; ++nt)
        Ph[tok * PP + nt * 16 + lr] = f2bs(sc[nt][rr] * inv);
      Ph[tok * PP + 112 + lr] = 0;
      Ph[tok * PP + 128 + (lr & 3)] = 0;
    }
  }
  __syncthreads();  // Vt (both strips) staged + P visible
  {
    const short* Vts = smem + sst * VTSH;
    f32x4 o2[2] = {f32x4{0, 0, 0, 0}, f32x4{0, 0, 0, 0}};
#pragma unroll
    for (int kt = 0; kt < 4; ++kt) {
      bf16x8 ap = ld8(Ph + (lr & 7) * PP + kt * 32 + kg * 8);
#pragma unroll
      for (int dt = 0; dt < 2; ++dt) {
        bf16x8 bv = ld8(Vts + (h * 32 + dt * 16 + lr) * VP + kt * 32 + kg * 8);
        o2[dt] = __builtin_amdgcn_mfma_f32_16x16x32_bf16(ap, bv, o2[dt], 0, 0, 0);
      }
    }
    if (kg < 2) {
#pragma unroll
      for (int dt = 0; dt < 2; ++dt)
#pragma unroll
        for (int rr = 0; rr < 4; ++rr)
          abuf[sst * 8 + kg * 4 + rr][h * 32 + dt * 16 + lr] =
              __float2bfloat16(o2[dt][rr]);
    }
  }
  __syncthreads();  // abuf complete

  // ---- tail: proj+LN2 -> w1+res+LN3 -> w2+relu+LN4 -> w3+res -> NCHW ----
  f32x4 acc;
  float x2f[4];

  auto gemm_lds = [&](const __hip_bfloat16* W) {
    bf16x8 af[4];
#pragma unroll
    for (int ks = 0; ks < 4; ++ks)
      af[ks] = *reinterpret_cast<const bf16x8*>(&abuf[lr][ks * 32 + kg * 8]);
    int o = wid * 16 + lr;
    const __hip_bfloat16* wp = W + o * 128 + kg * 8;
    acc = f32x4{0, 0, 0, 0};
#pragma unroll
    for (int ks = 0; ks < 4; ++ks) {
      bf16x8 bfr = *reinterpret_cast<const bf16x8*>(wp + ks * 32);
      acc = __builtin_amdgcn_mfma_f32_16x16x32_bf16(af[ks], bfr, acc, 0, 0, 0);
    }
  };
  auto ln_store = [&](const float* g, const float* be) {
    float ps[4], pq[4];
#pragma unroll
    for (int rr = 0; rr < 4; ++rr) {
      ps[rr] = acc[rr];
      pq[rr] = acc[rr] * acc[rr];
    }
#pragma unroll
    for (int rr = 0; rr < 4; ++rr)
#pragma unroll
      for (int off = 1; off < 16; off <<= 1) {
        ps[rr] += __shfl_xor(ps[rr], off);
        pq[rr] += __shfl_xor(pq[rr], off);
      }
    if (lr == 0)
#pragma unroll
      for (int rr = 0; rr < 4; ++rr)
        red[wid][kg * 4 + rr] = make_float2(ps[rr], pq[rr]);
    __syncthreads();
    float mu[4], rs[4];
#pragma unroll
    for (int rr = 0; rr < 4; ++rr) {
      int r16 = kg * 4 + rr;
      float ssum = 0.f, qsum = 0.f;
#pragma unroll
      for (int w = 0; w < 8; ++w) {
        float2 a = red[w][r16];
        ssum += a.x;
        qsum += a.y;
      }
      mu[rr] = ssum * (1.f / 128.f);
      float var = qsum * (1.f / 128.f) - mu[rr] * mu[rr];
      rs[rr] = rsqrtf(var + 1e-5f);
    }
    int o = wid * 16 + lr;
    float gv = g[o], bev = be[o];
#pragma unroll
    for (int rr = 0; rr < 4; ++rr)
      abuf[kg * 4 + rr][o] =
          __float2bfloat16((acc[rr] - mu[rr]) * rs[rr] * gv + bev);
    __syncthreads();
  };

  // stage 1: proj + LN2
  gemm_lds(wproj);
  {
    float bv = bproj[wid * 16 + lr];
#pragma unroll
    for (int rr = 0; rr < 4; ++rr) acc[rr] += bv;
  }
  ln_store(g2, be2);

  // stage 2: w1 + residual r, save x2, LN3
  gemm_lds(w1);
  {
    int o = wid * 16 + lr;
    float bv = b1[o];
#pragma unroll
    for (int rr = 0; rr < 4; ++rr) {
      int m = m0 + kg * 4 + rr;
      float v = acc[rr] + bv + r[(size_t)m * 128 + o];
      x2f[rr] = v;
      acc[rr] = v;
    }
  }
  ln_store(g3, be3);

  // stage 3: w2 + relu + LN4
  gemm_lds(w2);
  {
    float bv = b2[wid * 16 + lr];
#pragma unroll
    for (int rr = 0; rr < 4; ++rr) acc[rr] = fmaxf(acc[rr] + bv, 0.f);
  }
  ln_store(g4, be4);

  // stage 4: w3 + x2 residual -> NCHW f32 out
  gemm_lds(w3);
  {
    int o = wid * 16 + lr;
    float bv = b3[o];
#pragma unroll
    for (int rr = 0; rr < 4; ++rr) {
      int m = m0 + kg * 4 + rr;
      float v = acc[rr] + bv + x2f[rr];
      int bb = m >> 12, hw = m & 4095;
      out[(size_t)bb * 524288 + o * 4096 + hw] = v;
    }
  }
}

// ---------------- launch ----------------
extern "C" void kernel_launch(void* const* d_in, const int* in_sizes, int n_in,
                              void* d_out, int out_size, void* d_ws,
                              size_t ws_size, hipStream_t stream) {
  const float* x = (const float*)d_in[0];
  const float* g1 = (const float*)d_in[1];
  const float* be1 = (const float*)d_in[2];
  const float* g2 = (const float*)d_in[3];
  const float* be2 = (const float*)d_in[4];
  const float* g3 = (const float*)d_in[5];
  const float* be3 = (const float*)d_in[6];
  const float* g4 = (const float*)d_in[7];
  const float* be4 = (const float*)d_in[8];
  const float* qkv_w = (const float*)d_in[9];
  const float* qkv_b = (const float*)d_in[10];
  const float* rpb = (const float*)d_in[11];
  const float* proj_w = (const float*)d_in[12];
  const float* proj_b = (const float*)d_in[13];
  const float* w1 = (const float*)d_in[14];
  const float* bl1 = (const float*)d_in[15];
  const float* w2 = (const float*)d_in[16];
  const float* bl2 = (const float*)d_in[17];
  const float* w3 = (const float*)d_in[18];
  const float* bl3 = (const float*)d_in[19];

  char* ws = (char*)d_ws;
  __hip_bfloat16* wb = (__hip_bfloat16*)ws;               // [65536] tail weights bf16
  float* r = (float*)(ws + 262144);                       // [8192][128] f32
  __hip_bfloat16* qkvb = (__hip_bfloat16*)(ws + 4456448); // [8192][384] bf16

  k_qkvcw<<<512, 512, 0, stream>>>(x, g1, be1, qkv_b, qkv_w, proj_w, w1, w2,
                                   w3, wb, r, qkvb);
  k_fuse3<<<512, 512, 0, stream>>>(qkvb, rpb, r, wb, proj_b, g2, be2, bl1, g3,
                                   be3, bl2, g4, be4, bl3, (float*)d_out);
}